// Round 1
// baseline (1513.672 us; speedup 1.0000x reference)
//
#include <hip/hip_runtime.h>
#include <math.h>

#define B_SZ     2
#define L_SEQ    2048
#define DM       1024      // D_MODEL
#define DP       4384      // D_PROJ
#define DI       2048      // D_INNER
#define NH       32        // N_HEADS
#define HD       64        // HEAD_DIM
#define DS       128       // D_STATE
#define M_ROWS   (B_SZ * L_SEQ)   // 4096

// ---------------------------------------------------------------------------
// RMSNorm: one block per row of 1024, 256 threads, float4
// ---------------------------------------------------------------------------
__global__ __launch_bounds__(256) void k_rmsnorm(const float* __restrict__ x,
                                                 const float* __restrict__ w,
                                                 float* __restrict__ xn) {
    int row = blockIdx.x;
    int tid = threadIdx.x;
    const float4* x4 = (const float4*)(x + (long)row * DM);
    float4 v = x4[tid];
    float ss = v.x * v.x + v.y * v.y + v.z * v.z + v.w * v.w;
    #pragma unroll
    for (int off = 32; off > 0; off >>= 1) ss += __shfl_xor(ss, off, 64);
    __shared__ float sred[4];
    if ((tid & 63) == 0) sred[tid >> 6] = ss;
    __syncthreads();
    float tot = sred[0] + sred[1] + sred[2] + sred[3];
    float scale = rsqrtf(tot * (1.0f / (float)DM) + 1e-6f);
    const float4* w4 = (const float4*)w;
    float4 wv = w4[tid];
    float4 o;
    o.x = v.x * scale * wv.x;
    o.y = v.y * scale * wv.y;
    o.z = v.z * scale * wv.z;
    o.w = v.w * scale * wv.w;
    ((float4*)(xn + (long)row * DM))[tid] = o;
}

// ---------------------------------------------------------------------------
// fp32 tiled GEMM: C[M,N] = A[M,Kd] @ Bw[N,Kd]^T (+ resid[M,N] if non-null)
// 64x64 tile, BK=16, 256 threads, 4x4 microtile per thread.
// ---------------------------------------------------------------------------
__global__ __launch_bounds__(256, 2) void k_gemm(const float* __restrict__ A,
                                                 const float* __restrict__ Bw,
                                                 const float* __restrict__ resid,
                                                 float* __restrict__ C,
                                                 int M, int N, int Kd) {
    __shared__ float As[16][68];
    __shared__ float Bs[16][68];
    int tid = threadIdx.x;
    int tx = tid & 15, ty = tid >> 4;
    int bm = blockIdx.y * 64, bn = blockIdx.x * 64;

    int r  = tid >> 2;          // 0..63  (tile row for staging)
    int kq = (tid & 3) * 4;     // 0,4,8,12

    const float* Aload = A + (long)(bm + r) * Kd + kq;
    int brow = bn + r; if (brow >= N) brow = N - 1;   // clamp N-edge
    const float* Bload = Bw + (long)brow * Kd + kq;

    float acc[4][4] = {};

    for (int k0 = 0; k0 < Kd; k0 += 16) {
        float4 av = *(const float4*)(Aload + k0);
        float4 bv = *(const float4*)(Bload + k0);
        __syncthreads();   // previous iteration's reads complete
        As[kq + 0][r] = av.x; As[kq + 1][r] = av.y;
        As[kq + 2][r] = av.z; As[kq + 3][r] = av.w;
        Bs[kq + 0][r] = bv.x; Bs[kq + 1][r] = bv.y;
        Bs[kq + 2][r] = bv.z; Bs[kq + 3][r] = bv.w;
        __syncthreads();
        #pragma unroll
        for (int kk = 0; kk < 16; kk++) {
            float4 a4 = *(const float4*)&As[kk][ty * 4];
            float4 b4 = *(const float4*)&Bs[kk][tx * 4];
            float ar[4] = {a4.x, a4.y, a4.z, a4.w};
            float br[4] = {b4.x, b4.y, b4.z, b4.w};
            #pragma unroll
            for (int i = 0; i < 4; i++)
                #pragma unroll
                for (int j = 0; j < 4; j++)
                    acc[i][j] = fmaf(ar[i], br[j], acc[i][j]);
        }
    }

    int n0 = bn + tx * 4;
    if (n0 < N) {
        #pragma unroll
        for (int i = 0; i < 4; i++) {
            int m = bm + ty * 4 + i;
            float4 res;
            res.x = acc[i][0]; res.y = acc[i][1];
            res.z = acc[i][2]; res.w = acc[i][3];
            if (resid != nullptr) {
                float4 rv = *(const float4*)(resid + (long)m * N + n0);
                res.x += rv.x; res.y += rv.y; res.z += rv.z; res.w += rv.w;
            }
            *(float4*)(C + (long)m * N + n0) = res;
        }
    }
}

// ---------------------------------------------------------------------------
// Depthwise causal conv K=4 + bias + SiLU. x_ssm lives in proj[:, 2048:4096].
// One thread per (b, t, c). Output x_conv (B, L, DI) contiguous.
// ---------------------------------------------------------------------------
__global__ __launch_bounds__(256) void k_conv(const float* __restrict__ proj,
                                              const float* __restrict__ cw,
                                              const float* __restrict__ cb,
                                              float* __restrict__ xconv) {
    int idx = blockIdx.x * 256 + threadIdx.x;      // < 8,388,608
    int c = idx & (DI - 1);
    int t = (idx >> 11) & (L_SEQ - 1);
    int b = idx >> 22;
    const float* base = proj + (long)(b * L_SEQ) * DP + DI + c;
    float acc = cb[c];
    #pragma unroll
    for (int j = 0; j < 4; j++) {
        int tau = t - 3 + j;
        if (tau >= 0) acc = fmaf(cw[c * 4 + j], base[(long)tau * DP], acc);
    }
    xconv[idx] = acc / (1.0f + expf(-acc));        // SiLU
}

// ---------------------------------------------------------------------------
// dt = softplus(dt_raw + dt_bias), dA = exp(-exp(A_log)*dt). One thread per
// (b,t,h). dt_raw lives in proj[:, 4352:4384].
// ---------------------------------------------------------------------------
__global__ __launch_bounds__(256) void k_dt(const float* __restrict__ proj,
                                            const float* __restrict__ A_log,
                                            const float* __restrict__ dt_bias,
                                            float* __restrict__ dtb,
                                            float* __restrict__ dAb) {
    int idx = blockIdx.x * 256 + threadIdx.x;      // < 131072
    int hh = idx & 31;
    int row = idx >> 5;
    float xr = proj[(long)row * DP + 4352 + hh] + dt_bias[hh];
    float dt = (xr > 20.0f) ? xr : log1pf(expf(xr));
    dtb[idx] = dt;
    dAb[idx] = expf(-expf(A_log[hh]) * dt);
}

// ---------------------------------------------------------------------------
// SSM scan. Recurrence per (b,h,p,n): h = h*dA[b,t,h] + dt*x[b,t,h,p]*B[b,t,n]
//           y[b,t,h,p] = sum_n h*C[b,t,n]
// Grid: (b, h, p-quarter) = 2*32*4 = 256 blocks. 256 threads: thread owns
// 1 p-row x 8 n-cols of state. B/C/dtx/dA staged 8 timesteps at a time in LDS.
// y reduced over the 16 n-groups with shfl_xor(width=16).
// ---------------------------------------------------------------------------
__global__ __launch_bounds__(256) void k_scan(const float* __restrict__ proj,
                                              const float* __restrict__ xconv,
                                              const float* __restrict__ dtb,
                                              const float* __restrict__ dAb,
                                              float* __restrict__ yssm) {
    int blk = blockIdx.x;
    int ps = blk & 3;
    int hh = (blk >> 2) & 31;
    int b  = blk >> 7;
    int p0 = ps * 16;
    int tid = threadIdx.x;
    int ng = tid & 15;          // n-group (8 n each)
    int pg = tid >> 4;          // p within this block's 16-p slice

    __shared__ float sB[8][128];
    __shared__ float sC[8][128];
    __shared__ float sX[8][16];
    __shared__ float sdA[8];

    float hs[8] = {0.f, 0.f, 0.f, 0.f, 0.f, 0.f, 0.f, 0.f};
    long rowbase = (long)b * L_SEQ;

    for (int t0 = 0; t0 < L_SEQ; t0 += 8) {
        // ---- stage 8 timesteps ----
        {
            int i  = tid >> 5;
            int nq = (tid & 31) * 4;
            const float* prow = proj + (rowbase + t0 + i) * DP;
            *(float4*)&sB[i][nq] = *(const float4*)(prow + 4096 + nq);
            *(float4*)&sC[i][nq] = *(const float4*)(prow + 4224 + nq);
        }
        if (tid < 128) {
            int i = tid >> 4;
            int pp = tid & 15;
            long rr = rowbase + t0 + i;
            sX[i][pp] = dtb[rr * NH + hh] * xconv[rr * DI + hh * HD + p0 + pp];
        } else if (tid < 136) {
            int i = tid - 128;
            sdA[i] = dAb[(rowbase + t0 + i) * NH + hh];
        }
        __syncthreads();

        #pragma unroll
        for (int i = 0; i < 8; i++) {
            float4 b0 = *(const float4*)&sB[i][ng * 8];
            float4 b1 = *(const float4*)&sB[i][ng * 8 + 4];
            float4 c0 = *(const float4*)&sC[i][ng * 8];
            float4 c1 = *(const float4*)&sC[i][ng * 8 + 4];
            float xv = sX[i][pg];
            float a  = sdA[i];

            hs[0] = fmaf(hs[0], a, xv * b0.x);
            hs[1] = fmaf(hs[1], a, xv * b0.y);
            hs[2] = fmaf(hs[2], a, xv * b0.z);
            hs[3] = fmaf(hs[3], a, xv * b0.w);
            hs[4] = fmaf(hs[4], a, xv * b1.x);
            hs[5] = fmaf(hs[5], a, xv * b1.y);
            hs[6] = fmaf(hs[6], a, xv * b1.z);
            hs[7] = fmaf(hs[7], a, xv * b1.w);

            float ya = hs[0] * c0.x;
            ya = fmaf(hs[2], c0.z, ya);
            ya = fmaf(hs[4], c1.x, ya);
            ya = fmaf(hs[6], c1.z, ya);
            float yb = hs[1] * c0.y;
            yb = fmaf(hs[3], c0.w, yb);
            yb = fmaf(hs[5], c1.y, yb);
            yb = fmaf(hs[7], c1.w, yb);
            float yp = ya + yb;

            yp += __shfl_xor(yp, 1, 16);
            yp += __shfl_xor(yp, 2, 16);
            yp += __shfl_xor(yp, 4, 16);
            yp += __shfl_xor(yp, 8, 16);

            if (ng == 0)
                yssm[(rowbase + t0 + i) * DI + hh * HD + p0 + pg] = yp;
        }
        __syncthreads();
    }
}

// ---------------------------------------------------------------------------
// Gating: y = (y_ssm + D[h]*x_conv) * silu(z). In-place on yssm.
// ---------------------------------------------------------------------------
__global__ __launch_bounds__(256) void k_gate(const float* __restrict__ proj,
                                              const float* __restrict__ xconv,
                                              const float* __restrict__ Dv,
                                              float* __restrict__ y) {
    int idx = blockIdx.x * 256 + threadIdx.x;      // < 8,388,608
    int c = idx & (DI - 1);
    int row = idx >> 11;
    int hh = c >> 6;
    float yv = y[idx] + Dv[hh] * xconv[idx];
    float z = proj[(long)row * DP + c];
    y[idx] = yv * (z / (1.0f + expf(-z)));
}

// ---------------------------------------------------------------------------
extern "C" void kernel_launch(void* const* d_in, const int* in_sizes, int n_in,
                              void* d_out, int out_size, void* d_ws, size_t ws_size,
                              hipStream_t stream) {
    const float* x       = (const float*)d_in[0];
    const float* norm_w  = (const float*)d_in[1];
    const float* Wp      = (const float*)d_in[2];   // (4384, 1024)
    const float* cw      = (const float*)d_in[3];   // (2048, 1, 4)
    const float* cb      = (const float*)d_in[4];
    const float* A_log   = (const float*)d_in[5];
    const float* Dv      = (const float*)d_in[6];
    const float* dt_bias = (const float*)d_in[7];
    const float* Wo      = (const float*)d_in[8];   // (1024, 2048)
    float* out = (float*)d_out;

    float* ws    = (float*)d_ws;
    float* xn    = ws;                       //  4,194,304
    float* proj  = xn    +  4194304;         // 17,956,864
    float* xconv = proj  + 17956864;         //  8,388,608
    float* dtb   = xconv +  8388608;         //    131,072
    float* dAb   = dtb   +   131072;         //    131,072
    float* yb    = dAb   +   131072;         //  8,388,608
    // total 39,190,528 floats = 156.8 MB

    k_rmsnorm<<<M_ROWS, 256, 0, stream>>>(x, norm_w, xn);

    dim3 g1((DP + 63) / 64, M_ROWS / 64);
    k_gemm<<<g1, 256, 0, stream>>>(xn, Wp, nullptr, proj, M_ROWS, DP, DM);

    k_conv<<<(M_ROWS * DI) / 256, 256, 0, stream>>>(proj, cw, cb, xconv);
    k_dt<<<(M_ROWS * NH) / 256, 256, 0, stream>>>(proj, A_log, dt_bias, dtb, dAb);
    k_scan<<<B_SZ * NH * 4, 256, 0, stream>>>(proj, xconv, dtb, dAb, yb);
    k_gate<<<(M_ROWS * DI) / 256, 256, 0, stream>>>(proj, xconv, Dv, yb);

    dim3 g2(DM / 64, M_ROWS / 64);
    k_gemm<<<g2, 256, 0, stream>>>(yb, Wo, x, out, M_ROWS, DM, DI);
}

// Round 2
// 1129.293 us; speedup vs baseline: 1.3404x; 1.3404x over previous
//
#include <hip/hip_runtime.h>
#include <math.h>

#define B_SZ     2
#define L_SEQ    2048
#define DM       1024      // D_MODEL
#define DP       4384      // D_PROJ
#define DI       2048      // D_INNER
#define NH       32        // N_HEADS
#define HD       64        // HEAD_DIM
#define DS       128       // D_STATE
#define M_ROWS   (B_SZ * L_SEQ)   // 4096
#define QCH      64        // scan chunk length
#define NC       (L_SEQ / QCH)    // 32 chunks

// ---------------------------------------------------------------------------
// RMSNorm: one block per row of 1024, 256 threads, float4
// ---------------------------------------------------------------------------
__global__ __launch_bounds__(256) void k_rmsnorm(const float* __restrict__ x,
                                                 const float* __restrict__ w,
                                                 float* __restrict__ xn) {
    int row = blockIdx.x;
    int tid = threadIdx.x;
    const float4* x4 = (const float4*)(x + (long)row * DM);
    float4 v = x4[tid];
    float ss = v.x * v.x + v.y * v.y + v.z * v.z + v.w * v.w;
    #pragma unroll
    for (int off = 32; off > 0; off >>= 1) ss += __shfl_xor(ss, off, 64);
    __shared__ float sred[4];
    if ((tid & 63) == 0) sred[tid >> 6] = ss;
    __syncthreads();
    float tot = sred[0] + sred[1] + sred[2] + sred[3];
    float scale = rsqrtf(tot * (1.0f / (float)DM) + 1e-6f);
    const float4* w4 = (const float4*)w;
    float4 wv = w4[tid];
    float4 o;
    o.x = v.x * scale * wv.x;
    o.y = v.y * scale * wv.y;
    o.z = v.z * scale * wv.z;
    o.w = v.w * scale * wv.w;
    ((float4*)(xn + (long)row * DM))[tid] = o;
}

// ---------------------------------------------------------------------------
// fp32 tiled GEMM: C[M,N] = A[M,Kd] @ Bw[N,Kd]^T (+ resid[M,N] if non-null)
// ---------------------------------------------------------------------------
__global__ __launch_bounds__(256, 2) void k_gemm(const float* __restrict__ A,
                                                 const float* __restrict__ Bw,
                                                 const float* __restrict__ resid,
                                                 float* __restrict__ C,
                                                 int M, int N, int Kd) {
    __shared__ float As[16][68];
    __shared__ float Bs[16][68];
    int tid = threadIdx.x;
    int tx = tid & 15, ty = tid >> 4;
    int bm = blockIdx.y * 64, bn = blockIdx.x * 64;

    int r  = tid >> 2;
    int kq = (tid & 3) * 4;

    const float* Aload = A + (long)(bm + r) * Kd + kq;
    int brow = bn + r; if (brow >= N) brow = N - 1;
    const float* Bload = Bw + (long)brow * Kd + kq;

    float acc[4][4] = {};

    for (int k0 = 0; k0 < Kd; k0 += 16) {
        float4 av = *(const float4*)(Aload + k0);
        float4 bv = *(const float4*)(Bload + k0);
        __syncthreads();
        As[kq + 0][r] = av.x; As[kq + 1][r] = av.y;
        As[kq + 2][r] = av.z; As[kq + 3][r] = av.w;
        Bs[kq + 0][r] = bv.x; Bs[kq + 1][r] = bv.y;
        Bs[kq + 2][r] = bv.z; Bs[kq + 3][r] = bv.w;
        __syncthreads();
        #pragma unroll
        for (int kk = 0; kk < 16; kk++) {
            float4 a4 = *(const float4*)&As[kk][ty * 4];
            float4 b4 = *(const float4*)&Bs[kk][tx * 4];
            float ar[4] = {a4.x, a4.y, a4.z, a4.w};
            float br[4] = {b4.x, b4.y, b4.z, b4.w};
            #pragma unroll
            for (int i = 0; i < 4; i++)
                #pragma unroll
                for (int j = 0; j < 4; j++)
                    acc[i][j] = fmaf(ar[i], br[j], acc[i][j]);
        }
    }

    int n0 = bn + tx * 4;
    if (n0 < N) {
        #pragma unroll
        for (int i = 0; i < 4; i++) {
            int m = bm + ty * 4 + i;
            float4 res;
            res.x = acc[i][0]; res.y = acc[i][1];
            res.z = acc[i][2]; res.w = acc[i][3];
            if (resid != nullptr) {
                float4 rv = *(const float4*)(resid + (long)m * N + n0);
                res.x += rv.x; res.y += rv.y; res.z += rv.z; res.w += rv.w;
            }
            *(float4*)(C + (long)m * N + n0) = res;
        }
    }
}

// ---------------------------------------------------------------------------
// Depthwise causal conv K=4 + bias + SiLU
// ---------------------------------------------------------------------------
__global__ __launch_bounds__(256) void k_conv(const float* __restrict__ proj,
                                              const float* __restrict__ cw,
                                              const float* __restrict__ cb,
                                              float* __restrict__ xconv) {
    int idx = blockIdx.x * 256 + threadIdx.x;
    int c = idx & (DI - 1);
    int t = (idx >> 11) & (L_SEQ - 1);
    int b = idx >> 22;
    const float* base = proj + (long)(b * L_SEQ) * DP + DI + c;
    float acc = cb[c];
    #pragma unroll
    for (int j = 0; j < 4; j++) {
        int tau = t - 3 + j;
        if (tau >= 0) acc = fmaf(cw[c * 4 + j], base[(long)tau * DP], acc);
    }
    xconv[idx] = acc / (1.0f + expf(-acc));
}

// ---------------------------------------------------------------------------
// dt = softplus(dt_raw + dt_bias), dA = exp(-exp(A_log)*dt)
// ---------------------------------------------------------------------------
__global__ __launch_bounds__(256) void k_dt(const float* __restrict__ proj,
                                            const float* __restrict__ A_log,
                                            const float* __restrict__ dt_bias,
                                            float* __restrict__ dtb,
                                            float* __restrict__ dAb) {
    int idx = blockIdx.x * 256 + threadIdx.x;
    int hh = idx & 31;
    int row = idx >> 5;
    float xr = proj[(long)row * DP + 4352 + hh] + dt_bias[hh];
    float dt = (xr > 20.0f) ? xr : log1pf(expf(xr));
    dtb[idx] = dt;
    dAb[idx] = expf(-expf(A_log[hh]) * dt);
}

// ---------------------------------------------------------------------------
// Per-chunk cumulative log-decay: clog[b,t,h] = sum_{s=chunk_start..t} -exp(A_log)*dt_s
// One thread per (b,h,chunk) = 2048 threads.
// ---------------------------------------------------------------------------
__global__ __launch_bounds__(256) void k_cumlog(const float* __restrict__ dtb,
                                                const float* __restrict__ A_log,
                                                float* __restrict__ clog) {
    int idx = blockIdx.x * 256 + threadIdx.x;   // < 2048
    int c  = idx & 31;
    int hh = (idx >> 5) & 31;
    int b  = idx >> 10;
    float la = -expf(A_log[hh]);
    long base = ((long)b * L_SEQ + c * QCH) * NH + hh;
    float run = 0.0f;
    for (int t = 0; t < QCH; t++) {
        run += la * dtb[base + (long)t * NH];
        clog[base + (long)t * NH] = run;
    }
}

// ---------------------------------------------------------------------------
// Phase A: local scan per chunk (h starts at 0). Grid: b*h*chunk*p-half =
// 2*32*32*2 = 4096 blocks, 256 threads: thread = 1 p x 16 n. Writes intra-chunk
// y to yssm and the chunk's final local state to Sloc[b,h,c,p,n].
// LDS B/C rows swizzled (+4 floats per 16) so the stride-16 b128 reads are
// conflict-free across the 8 ng lanes.
// ---------------------------------------------------------------------------
__global__ __launch_bounds__(256) void k_scan_local(const float* __restrict__ proj,
                                                    const float* __restrict__ xconv,
                                                    const float* __restrict__ dtb,
                                                    const float* __restrict__ dAb,
                                                    float* __restrict__ yssm,
                                                    float* __restrict__ Sloc) {
    int blk = blockIdx.x;
    int ph = blk & 1;
    int c  = (blk >> 1) & 31;
    int hh = (blk >> 6) & 31;
    int b  = blk >> 11;
    int p0 = ph * 32;
    int tid = threadIdx.x;
    int ng = tid & 7;        // 8 n-groups of 16
    int pg = tid >> 3;       // 0..31

    __shared__ float sB[8][160];   // 128 data + swizzle pad (4 per 16)
    __shared__ float sC[8][160];
    __shared__ float sX[8][32];
    __shared__ float sdA[8];

    float hs[16];
    #pragma unroll
    for (int k = 0; k < 16; k++) hs[k] = 0.0f;

    long rowbase = (long)b * L_SEQ + c * QCH;

    for (int t0 = 0; t0 < QCH; t0 += 8) {
        {
            int i = tid >> 5;
            int n = (tid & 31) * 4;
            int nsw = n + (n >> 4) * 4;
            const float* prow = proj + (rowbase + t0 + i) * DP;
            *(float4*)&sB[i][nsw] = *(const float4*)(prow + 4096 + n);
            *(float4*)&sC[i][nsw] = *(const float4*)(prow + 4224 + n);
        }
        {
            int i = tid >> 5;
            int pp = tid & 31;
            long rr = rowbase + t0 + i;
            sX[i][pp] = dtb[rr * NH + hh] * xconv[rr * DI + hh * HD + p0 + pp];
        }
        if (tid < 8) sdA[tid] = dAb[(rowbase + t0 + tid) * NH + hh];
        __syncthreads();

        #pragma unroll
        for (int i = 0; i < 8; i++) {
            int nb = ng * 20;
            float4 B0 = *(const float4*)&sB[i][nb];
            float4 B1 = *(const float4*)&sB[i][nb + 4];
            float4 B2 = *(const float4*)&sB[i][nb + 8];
            float4 B3 = *(const float4*)&sB[i][nb + 12];
            float4 C0 = *(const float4*)&sC[i][nb];
            float4 C1 = *(const float4*)&sC[i][nb + 4];
            float4 C2 = *(const float4*)&sC[i][nb + 8];
            float4 C3 = *(const float4*)&sC[i][nb + 12];
            float xv = sX[i][pg];
            float a  = sdA[i];

            hs[0]  = fmaf(hs[0],  a, xv * B0.x);
            hs[1]  = fmaf(hs[1],  a, xv * B0.y);
            hs[2]  = fmaf(hs[2],  a, xv * B0.z);
            hs[3]  = fmaf(hs[3],  a, xv * B0.w);
            hs[4]  = fmaf(hs[4],  a, xv * B1.x);
            hs[5]  = fmaf(hs[5],  a, xv * B1.y);
            hs[6]  = fmaf(hs[6],  a, xv * B1.z);
            hs[7]  = fmaf(hs[7],  a, xv * B1.w);
            hs[8]  = fmaf(hs[8],  a, xv * B2.x);
            hs[9]  = fmaf(hs[9],  a, xv * B2.y);
            hs[10] = fmaf(hs[10], a, xv * B2.z);
            hs[11] = fmaf(hs[11], a, xv * B2.w);
            hs[12] = fmaf(hs[12], a, xv * B3.x);
            hs[13] = fmaf(hs[13], a, xv * B3.y);
            hs[14] = fmaf(hs[14], a, xv * B3.z);
            hs[15] = fmaf(hs[15], a, xv * B3.w);

            float y0 = fmaf(hs[0],  C0.x, hs[1]  * C0.y);
            float y1 = fmaf(hs[2],  C0.z, hs[3]  * C0.w);
            float y2 = fmaf(hs[4],  C1.x, hs[5]  * C1.y);
            float y3 = fmaf(hs[6],  C1.z, hs[7]  * C1.w);
            float y4 = fmaf(hs[8],  C2.x, hs[9]  * C2.y);
            float y5 = fmaf(hs[10], C2.z, hs[11] * C2.w);
            float y6 = fmaf(hs[12], C3.x, hs[13] * C3.y);
            float y7 = fmaf(hs[14], C3.z, hs[15] * C3.w);
            float yp = ((y0 + y1) + (y2 + y3)) + ((y4 + y5) + (y6 + y7));

            yp += __shfl_xor(yp, 1, 8);
            yp += __shfl_xor(yp, 2, 8);
            yp += __shfl_xor(yp, 4, 8);

            if (ng == 0)
                yssm[(rowbase + t0 + i) * DI + hh * HD + p0 + pg] = yp;
        }
        __syncthreads();
    }

    // store chunk-final local state
    long sbase = (((long)(b * NH + hh) * NC + c) * HD + (p0 + pg)) * DS + ng * 16;
    float4 s0 = {hs[0],  hs[1],  hs[2],  hs[3]};
    float4 s1 = {hs[4],  hs[5],  hs[6],  hs[7]};
    float4 s2 = {hs[8],  hs[9],  hs[10], hs[11]};
    float4 s3 = {hs[12], hs[13], hs[14], hs[15]};
    *(float4*)&Sloc[sbase]      = s0;
    *(float4*)&Sloc[sbase + 4]  = s1;
    *(float4*)&Sloc[sbase + 8]  = s2;
    *(float4*)&Sloc[sbase + 12] = s3;
}

// ---------------------------------------------------------------------------
// Phase B: sequential carry over the 32 chunks. In-place on Sloc: replaces
// S_c with H_in (state entering chunk c). One thread per (b,h,p,n) = 524288.
// ---------------------------------------------------------------------------
__global__ __launch_bounds__(256) void k_carry(float* __restrict__ Sloc,
                                               const float* __restrict__ clog) {
    int idx = blockIdx.x * 256 + threadIdx.x;   // < 524288
    int n  = idx & 127;
    int p  = (idx >> 7) & 63;
    int hh = (idx >> 13) & 31;
    int b  = idx >> 18;
    long base = ((long)(b * NH + hh) * NC) * (HD * DS) + p * DS + n;
    float T = 0.0f;
    for (int c = 0; c < NC; c++) {
        float lam = expf(clog[((long)b * L_SEQ + c * QCH + QCH - 1) * NH + hh]);
        long a = base + (long)c * (HD * DS);
        float S = Sloc[a];
        Sloc[a] = T;                 // H_in for chunk c
        T = fmaf(T, lam, S);
    }
}

// ---------------------------------------------------------------------------
// Phase C: inter-chunk correction. y[b,t,h,p] += exp(clog_t) * (C_t . Hin[p,:])
// One block per (b,h,chunk): (64t x 128n) @ (128n x 64p) with LDS tiles.
// ---------------------------------------------------------------------------
__global__ __launch_bounds__(256, 2) void k_fix(const float* __restrict__ proj,
                                                const float* __restrict__ Sloc,
                                                const float* __restrict__ clog,
                                                float* __restrict__ yssm) {
    int blk = blockIdx.x;
    int c  = blk & 31;
    int hh = (blk >> 5) & 31;
    int b  = blk >> 10;

    __shared__ float sH[64 * 132];
    __shared__ float sCt[64 * 132];
    __shared__ float sP[64];

    int tid = threadIdx.x;
    long hbase = ((long)(b * NH + hh) * NC + c) * (HD * DS);
    long rowbase = (long)b * L_SEQ + c * QCH;

    #pragma unroll
    for (int j = 0; j < 8; j++) {
        int off = j * 1024 + tid * 4;
        int p = off >> 7, n = off & 127;
        *(float4*)&sH[p * 132 + n] = *(const float4*)&Sloc[hbase + off];
    }
    #pragma unroll
    for (int j = 0; j < 8; j++) {
        int off = j * 1024 + tid * 4;
        int t = off >> 7, n = off & 127;
        *(float4*)&sCt[t * 132 + n] = *(const float4*)&proj[(rowbase + t) * DP + 4224 + n];
    }
    if (tid < 64) sP[tid] = expf(clog[(rowbase + tid) * NH + hh]);
    __syncthreads();

    int tx = tid & 15, ty = tid >> 4;
    int pB = tx * 4, tB = ty * 4;
    float acc[4][4] = {};

    for (int n = 0; n < 128; n += 4) {
        float4 cv[4], hv[4];
        #pragma unroll
        for (int i = 0; i < 4; i++) cv[i] = *(const float4*)&sCt[(tB + i) * 132 + n];
        #pragma unroll
        for (int j = 0; j < 4; j++) hv[j] = *(const float4*)&sH[(pB + j) * 132 + n];
        #pragma unroll
        for (int i = 0; i < 4; i++)
            #pragma unroll
            for (int j = 0; j < 4; j++) {
                acc[i][j] = fmaf(cv[i].x, hv[j].x, acc[i][j]);
                acc[i][j] = fmaf(cv[i].y, hv[j].y, acc[i][j]);
                acc[i][j] = fmaf(cv[i].z, hv[j].z, acc[i][j]);
                acc[i][j] = fmaf(cv[i].w, hv[j].w, acc[i][j]);
            }
    }

    #pragma unroll
    for (int i = 0; i < 4; i++) {
        long yoff = (rowbase + tB + i) * DI + hh * HD + pB;
        float pm = sP[tB + i];
        float4 yv = *(const float4*)&yssm[yoff];
        yv.x += pm * acc[i][0];
        yv.y += pm * acc[i][1];
        yv.z += pm * acc[i][2];
        yv.w += pm * acc[i][3];
        *(float4*)&yssm[yoff] = yv;
    }
}

// ---------------------------------------------------------------------------
// Gating: y = (y_ssm + D[h]*x_conv) * silu(z)
// ---------------------------------------------------------------------------
__global__ __launch_bounds__(256) void k_gate(const float* __restrict__ proj,
                                              const float* __restrict__ xconv,
                                              const float* __restrict__ Dv,
                                              float* __restrict__ y) {
    int idx = blockIdx.x * 256 + threadIdx.x;
    int c = idx & (DI - 1);
    int row = idx >> 11;
    int hh = c >> 6;
    float yv = y[idx] + Dv[hh] * xconv[idx];
    float z = proj[(long)row * DP + c];
    y[idx] = yv * (z / (1.0f + expf(-z)));
}

// ---------------------------------------------------------------------------
extern "C" void kernel_launch(void* const* d_in, const int* in_sizes, int n_in,
                              void* d_out, int out_size, void* d_ws, size_t ws_size,
                              hipStream_t stream) {
    const float* x       = (const float*)d_in[0];
    const float* norm_w  = (const float*)d_in[1];
    const float* Wp      = (const float*)d_in[2];
    const float* cw      = (const float*)d_in[3];
    const float* cb      = (const float*)d_in[4];
    const float* A_log   = (const float*)d_in[5];
    const float* Dv      = (const float*)d_in[6];
    const float* dt_bias = (const float*)d_in[7];
    const float* Wo      = (const float*)d_in[8];
    float* out = (float*)d_out;

    float* ws    = (float*)d_ws;
    float* xn    = ws;                       //  4,194,304
    float* proj  = xn    +  4194304;         // 17,956,864
    float* xconv = proj  + 17956864;         //  8,388,608
    float* dtb   = xconv +  8388608;         //    131,072
    float* dAb   = dtb   +   131072;         //    131,072
    float* clog  = dAb   +   131072;         //    131,072
    float* yb    = clog  +   131072;         //  8,388,608
    float* Sloc  = yb    +  8388608;         // 16,777,216
    // total ~56.1M floats = 224 MB

    k_rmsnorm<<<M_ROWS, 256, 0, stream>>>(x, norm_w, xn);

    dim3 g1((DP + 63) / 64, M_ROWS / 64);
    k_gemm<<<g1, 256, 0, stream>>>(xn, Wp, nullptr, proj, M_ROWS, DP, DM);

    k_conv<<<(M_ROWS * DI) / 256, 256, 0, stream>>>(proj, cw, cb, xconv);
    k_dt<<<(M_ROWS * NH) / 256, 256, 0, stream>>>(proj, A_log, dt_bias, dtb, dAb);
    k_cumlog<<<8, 256, 0, stream>>>(dtb, A_log, clog);

    k_scan_local<<<B_SZ * NH * NC * 2, 256, 0, stream>>>(proj, xconv, dtb, dAb, yb, Sloc);
    k_carry<<<(B_SZ * NH * HD * DS) / 256, 256, 0, stream>>>(Sloc, clog);
    k_fix<<<B_SZ * NH * NC, 256, 0, stream>>>(proj, Sloc, clog, yb);

    k_gate<<<(M_ROWS * DI) / 256, 256, 0, stream>>>(proj, xconv, Dv, yb);

    dim3 g2(DM / 64, M_ROWS / 64);
    k_gemm<<<g2, 256, 0, stream>>>(yb, Wo, x, out, M_ROWS, DM, DI);
}

// Round 5
// 506.262 us; speedup vs baseline: 2.9899x; 2.2306x over previous
//
#include <hip/hip_runtime.h>
#include <math.h>

#define B_SZ     2
#define L_SEQ    2048
#define DM       1024      // D_MODEL
#define DP       4384      // D_PROJ (logical)
#define PS       4480      // proj padded stride (35 * 128)
#define DI       2048      // D_INNER
#define NH       32        // N_HEADS
#define HD       64        // HEAD_DIM
#define DS       128       // D_STATE
#define M_ROWS   (B_SZ * L_SEQ)   // 4096
#define QCH      64        // scan chunk length
#define NC       (L_SEQ / QCH)    // 32 chunks

typedef __bf16 bf16x8 __attribute__((ext_vector_type(8)));
typedef __bf16 bf16x4 __attribute__((ext_vector_type(4)));
typedef float  f32x4  __attribute__((ext_vector_type(4)));

// ---------------------------------------------------------------------------
// fp32 -> bf16 conversion (weights), float4 -> bf16x4
// ---------------------------------------------------------------------------
__global__ __launch_bounds__(256) void k_f2b(const float* __restrict__ src,
                                             __bf16* __restrict__ dst, int n4) {
    int i = blockIdx.x * 256 + threadIdx.x;
    if (i < n4) {
        float4 v = ((const float4*)src)[i];
        bf16x4 o = { (__bf16)v.x, (__bf16)v.y, (__bf16)v.z, (__bf16)v.w };
        ((bf16x4*)dst)[i] = o;
    }
}

// ---------------------------------------------------------------------------
// RMSNorm: one block per row of 1024, 256 threads, float4 in, bf16 out
// ---------------------------------------------------------------------------
__global__ __launch_bounds__(256) void k_rmsnorm(const float* __restrict__ x,
                                                 const float* __restrict__ w,
                                                 __bf16* __restrict__ xn) {
    int row = blockIdx.x;
    int tid = threadIdx.x;
    const float4* x4 = (const float4*)(x + (long)row * DM);
    float4 v = x4[tid];
    float ss = v.x * v.x + v.y * v.y + v.z * v.z + v.w * v.w;
    #pragma unroll
    for (int off = 32; off > 0; off >>= 1) ss += __shfl_xor(ss, off, 64);
    __shared__ float sred[4];
    if ((tid & 63) == 0) sred[tid >> 6] = ss;
    __syncthreads();
    float tot = sred[0] + sred[1] + sred[2] + sred[3];
    float scale = rsqrtf(tot * (1.0f / (float)DM) + 1e-6f);
    const float4* w4 = (const float4*)w;
    float4 wv = w4[tid];
    bf16x4 o = { (__bf16)(v.x * scale * wv.x), (__bf16)(v.y * scale * wv.y),
                 (__bf16)(v.z * scale * wv.z), (__bf16)(v.w * scale * wv.w) };
    ((bf16x4*)(xn + (long)row * DM))[tid] = o;
}

// ---------------------------------------------------------------------------
// bf16 MFMA GEMM (m93 structure, register staging): C = A @ W^T (+resid).
// 128x128 tile, BK=32, 256 threads = 4 waves, 4x4 mfma_f32_16x16x32_bf16.
// LDS row stride 40 elems (80 B; 2-way bank alias = free per m136).
// ---------------------------------------------------------------------------
__global__ __launch_bounds__(256) void k_gemm_bf(const __bf16* __restrict__ A,
                                                 const __bf16* __restrict__ W,
                                                 const float* __restrict__ resid,
                                                 float* __restrict__ C,
                                                 int Nw, int K, int ldc) {
    __shared__ __align__(16) __bf16 As[128 * 40];
    __shared__ __align__(16) __bf16 Bs[128 * 40];
    int t = threadIdx.x;
    int bm = blockIdx.y * 128, bn = blockIdx.x * 128;

    int r0 = t >> 2;                 // rows 0..63
    int c0 = (t & 3) * 8;            // k offset 0/8/16/24
    int r1 = r0 + 64;
    const __bf16* Ag0 = A + (long)(bm + r0) * K + c0;
    const __bf16* Ag1 = A + (long)(bm + r1) * K + c0;
    int br0 = bn + r0; if (br0 >= Nw) br0 = Nw - 1;
    int br1 = bn + r1; if (br1 >= Nw) br1 = Nw - 1;
    const __bf16* Wg0 = W + (long)br0 * K + c0;
    const __bf16* Wg1 = W + (long)br1 * K + c0;
    __bf16* Al0 = As + r0 * 40 + c0;
    __bf16* Al1 = As + r1 * 40 + c0;
    __bf16* Bl0 = Bs + r0 * 40 + c0;
    __bf16* Bl1 = Bs + r1 * 40 + c0;

    // compute-side: A-frag lane layout m=lane&15, k=(lane>>4)*8+j (m120-verified)
    int lane = t & 63, w = t >> 6;
    int wm = (w & 1) * 64, wn = (w >> 1) * 64;
    int ln = lane & 15;
    int kc = (lane >> 4) * 8;
    const __bf16* Ar = As + (wm + ln) * 40 + kc;
    const __bf16* Br = Bs + (wn + ln) * 40 + kc;

    f32x4 acc[4][4] = {};

    for (int k0 = 0; k0 < K; k0 += 32) {
        bf16x8 a0 = *(const bf16x8*)(Ag0 + k0);
        bf16x8 a1 = *(const bf16x8*)(Ag1 + k0);
        bf16x8 b0 = *(const bf16x8*)(Wg0 + k0);
        bf16x8 b1 = *(const bf16x8*)(Wg1 + k0);
        __syncthreads();
        *(bf16x8*)Al0 = a0;
        *(bf16x8*)Al1 = a1;
        *(bf16x8*)Bl0 = b0;
        *(bf16x8*)Bl1 = b1;
        __syncthreads();

        bf16x8 af[4], bfr[4];
        #pragma unroll
        for (int i = 0; i < 4; i++) af[i]  = *(const bf16x8*)(Ar + i * 16 * 40);
        #pragma unroll
        for (int j = 0; j < 4; j++) bfr[j] = *(const bf16x8*)(Br + j * 16 * 40);
        #pragma unroll
        for (int i = 0; i < 4; i++)
            #pragma unroll
            for (int j = 0; j < 4; j++)
                acc[i][j] = __builtin_amdgcn_mfma_f32_16x16x32_bf16(
                                af[i], bfr[j], acc[i][j], 0, 0, 0);
    }

    // epilogue: C/D layout col=lane&15, row=(lane>>4)*4+reg (m89-verified)
    #pragma unroll
    for (int i = 0; i < 4; i++) {
        #pragma unroll
        for (int r = 0; r < 4; r++) {
            int m = bm + wm + i * 16 + (lane >> 4) * 4 + r;
            long off = (long)m * ldc + bn + wn + ln;
            #pragma unroll
            for (int j = 0; j < 4; j++) {
                float v = acc[i][j][r];
                if (resid != nullptr) v += resid[off + j * 16];
                C[off + j * 16] = v;
            }
        }
    }
}

// ---------------------------------------------------------------------------
// Depthwise causal conv K=4 + bias + SiLU. x_ssm at proj[:, 2048:4096].
// ---------------------------------------------------------------------------
__global__ __launch_bounds__(256) void k_conv(const float* __restrict__ proj,
                                              const float* __restrict__ cw,
                                              const float* __restrict__ cb,
                                              float* __restrict__ xconv) {
    int idx = blockIdx.x * 256 + threadIdx.x;
    int c = idx & (DI - 1);
    int t = (idx >> 11) & (L_SEQ - 1);
    int b = idx >> 22;
    const float* base = proj + (long)(b * L_SEQ) * PS + DI + c;
    float acc = cb[c];
    #pragma unroll
    for (int j = 0; j < 4; j++) {
        int tau = t - 3 + j;
        if (tau >= 0) acc = fmaf(cw[c * 4 + j], base[(long)tau * PS], acc);
    }
    xconv[idx] = acc / (1.0f + expf(-acc));
}

// ---------------------------------------------------------------------------
// dt = softplus(dt_raw + dt_bias), dA = exp(-exp(A_log)*dt)
// ---------------------------------------------------------------------------
__global__ __launch_bounds__(256) void k_dt(const float* __restrict__ proj,
                                            const float* __restrict__ A_log,
                                            const float* __restrict__ dt_bias,
                                            float* __restrict__ dtb,
                                            float* __restrict__ dAb) {
    int idx = blockIdx.x * 256 + threadIdx.x;
    int hh = idx & 31;
    int row = idx >> 5;
    float xr = proj[(long)row * PS + 4352 + hh] + dt_bias[hh];
    float dt = (xr > 20.0f) ? xr : log1pf(expf(xr));
    dtb[idx] = dt;
    dAb[idx] = expf(-expf(A_log[hh]) * dt);
}

// ---------------------------------------------------------------------------
// Per-chunk cumulative log-decay
// ---------------------------------------------------------------------------
__global__ __launch_bounds__(256) void k_cumlog(const float* __restrict__ dtb,
                                                const float* __restrict__ A_log,
                                                float* __restrict__ clog) {
    int idx = blockIdx.x * 256 + threadIdx.x;   // < 2048
    int c  = idx & 31;
    int hh = (idx >> 5) & 31;
    int b  = idx >> 10;
    float la = -expf(A_log[hh]);
    long base = ((long)b * L_SEQ + c * QCH) * NH + hh;
    float run = 0.0f;
    for (int t = 0; t < QCH; t++) {
        run += la * dtb[base + (long)t * NH];
        clog[base + (long)t * NH] = run;
    }
}

// ---------------------------------------------------------------------------
// Phase A: local scan per chunk (round-2 verified, PS stride)
// ---------------------------------------------------------------------------
__global__ __launch_bounds__(256) void k_scan_local(const float* __restrict__ proj,
                                                    const float* __restrict__ xconv,
                                                    const float* __restrict__ dtb,
                                                    const float* __restrict__ dAb,
                                                    float* __restrict__ yssm,
                                                    float* __restrict__ Sloc) {
    int blk = blockIdx.x;
    int ph = blk & 1;
    int c  = (blk >> 1) & 31;
    int hh = (blk >> 6) & 31;
    int b  = blk >> 11;
    int p0 = ph * 32;
    int tid = threadIdx.x;
    int ng = tid & 7;
    int pg = tid >> 3;

    __shared__ float sB[8][160];
    __shared__ float sC[8][160];
    __shared__ float sX[8][32];
    __shared__ float sdA[8];

    float hs[16];
    #pragma unroll
    for (int k = 0; k < 16; k++) hs[k] = 0.0f;

    long rowbase = (long)b * L_SEQ + c * QCH;

    for (int t0 = 0; t0 < QCH; t0 += 8) {
        {
            int i = tid >> 5;
            int n = (tid & 31) * 4;
            int nsw = n + (n >> 4) * 4;
            const float* prow = proj + (rowbase + t0 + i) * PS;
            *(float4*)&sB[i][nsw] = *(const float4*)(prow + 4096 + n);
            *(float4*)&sC[i][nsw] = *(const float4*)(prow + 4224 + n);
        }
        {
            int i = tid >> 5;
            int pp = tid & 31;
            long rr = rowbase + t0 + i;
            sX[i][pp] = dtb[rr * NH + hh] * xconv[rr * DI + hh * HD + p0 + pp];
        }
        if (tid < 8) sdA[tid] = dAb[(rowbase + t0 + tid) * NH + hh];
        __syncthreads();

        #pragma unroll
        for (int i = 0; i < 8; i++) {
            int nb = ng * 20;
            float4 B0 = *(const float4*)&sB[i][nb];
            float4 B1 = *(const float4*)&sB[i][nb + 4];
            float4 B2 = *(const float4*)&sB[i][nb + 8];
            float4 B3 = *(const float4*)&sB[i][nb + 12];
            float4 C0 = *(const float4*)&sC[i][nb];
            float4 C1 = *(const float4*)&sC[i][nb + 4];
            float4 C2 = *(const float4*)&sC[i][nb + 8];
            float4 C3 = *(const float4*)&sC[i][nb + 12];
            float xv = sX[i][pg];
            float a  = sdA[i];

            hs[0]  = fmaf(hs[0],  a, xv * B0.x);
            hs[1]  = fmaf(hs[1],  a, xv * B0.y);
            hs[2]  = fmaf(hs[2],  a, xv * B0.z);
            hs[3]  = fmaf(hs[3],  a, xv * B0.w);
            hs[4]  = fmaf(hs[4],  a, xv * B1.x);
            hs[5]  = fmaf(hs[5],  a, xv * B1.y);
            hs[6]  = fmaf(hs[6],  a, xv * B1.z);
            hs[7]  = fmaf(hs[7],  a, xv * B1.w);
            hs[8]  = fmaf(hs[8],  a, xv * B2.x);
            hs[9]  = fmaf(hs[9],  a, xv * B2.y);
            hs[10] = fmaf(hs[10], a, xv * B2.z);
            hs[11] = fmaf(hs[11], a, xv * B2.w);
            hs[12] = fmaf(hs[12], a, xv * B3.x);
            hs[13] = fmaf(hs[13], a, xv * B3.y);
            hs[14] = fmaf(hs[14], a, xv * B3.z);
            hs[15] = fmaf(hs[15], a, xv * B3.w);

            float y0 = fmaf(hs[0],  C0.x, hs[1]  * C0.y);
            float y1 = fmaf(hs[2],  C0.z, hs[3]  * C0.w);
            float y2 = fmaf(hs[4],  C1.x, hs[5]  * C1.y);
            float y3 = fmaf(hs[6],  C1.z, hs[7]  * C1.w);
            float y4 = fmaf(hs[8],  C2.x, hs[9]  * C2.y);
            float y5 = fmaf(hs[10], C2.z, hs[11] * C2.w);
            float y6 = fmaf(hs[12], C3.x, hs[13] * C3.y);
            float y7 = fmaf(hs[14], C3.z, hs[15] * C3.w);
            float yp = ((y0 + y1) + (y2 + y3)) + ((y4 + y5) + (y6 + y7));

            yp += __shfl_xor(yp, 1, 8);
            yp += __shfl_xor(yp, 2, 8);
            yp += __shfl_xor(yp, 4, 8);

            if (ng == 0)
                yssm[(rowbase + t0 + i) * DI + hh * HD + p0 + pg] = yp;
        }
        __syncthreads();
    }

    long sbase = (((long)(b * NH + hh) * NC + c) * HD + (p0 + pg)) * DS + ng * 16;
    float4 s0 = {hs[0],  hs[1],  hs[2],  hs[3]};
    float4 s1 = {hs[4],  hs[5],  hs[6],  hs[7]};
    float4 s2 = {hs[8],  hs[9],  hs[10], hs[11]};
    float4 s3 = {hs[12], hs[13], hs[14], hs[15]};
    *(float4*)&Sloc[sbase]      = s0;
    *(float4*)&Sloc[sbase + 4]  = s1;
    *(float4*)&Sloc[sbase + 8]  = s2;
    *(float4*)&Sloc[sbase + 12] = s3;
}

// ---------------------------------------------------------------------------
// Phase B: sequential carry over chunks (in-place: S_c -> H_in(c))
// ---------------------------------------------------------------------------
__global__ __launch_bounds__(256) void k_carry(float* __restrict__ Sloc,
                                               const float* __restrict__ clog) {
    int idx = blockIdx.x * 256 + threadIdx.x;   // < 524288
    int n  = idx & 127;
    int p  = (idx >> 7) & 63;
    int hh = (idx >> 13) & 31;
    int b  = idx >> 18;
    long base = ((long)(b * NH + hh) * NC) * (HD * DS) + p * DS + n;
    float T = 0.0f;
    for (int c = 0; c < NC; c++) {
        float lam = expf(clog[((long)b * L_SEQ + c * QCH + QCH - 1) * NH + hh]);
        long a = base + (long)c * (HD * DS);
        float S = Sloc[a];
        Sloc[a] = T;
        T = fmaf(T, lam, S);
    }
}

// ---------------------------------------------------------------------------
// Phase C: inter-chunk correction y += exp(clog_t) * (C_t . Hin[p,:])
// ---------------------------------------------------------------------------
__global__ __launch_bounds__(256, 2) void k_fix(const float* __restrict__ proj,
                                                const float* __restrict__ Sloc,
                                                const float* __restrict__ clog,
                                                float* __restrict__ yssm) {
    int blk = blockIdx.x;
    int c  = blk & 31;
    int hh = (blk >> 5) & 31;
    int b  = blk >> 10;

    __shared__ float sH[64 * 132];
    __shared__ float sCt[64 * 132];
    __shared__ float sP[64];

    int tid = threadIdx.x;
    long hbase = ((long)(b * NH + hh) * NC + c) * (HD * DS);
    long rowbase = (long)b * L_SEQ + c * QCH;

    #pragma unroll
    for (int j = 0; j < 8; j++) {
        int off = j * 1024 + tid * 4;
        int p = off >> 7, n = off & 127;
        *(float4*)&sH[p * 132 + n] = *(const float4*)&Sloc[hbase + off];
    }
    #pragma unroll
    for (int j = 0; j < 8; j++) {
        int off = j * 1024 + tid * 4;
        int t = off >> 7, n = off & 127;
        *(float4*)&sCt[t * 132 + n] = *(const float4*)&proj[(rowbase + t) * PS + 4224 + n];
    }
    if (tid < 64) sP[tid] = expf(clog[(rowbase + tid) * NH + hh]);
    __syncthreads();

    int tx = tid & 15, ty = tid >> 4;
    int pB = tx * 4, tB = ty * 4;
    float acc[4][4] = {};

    for (int n = 0; n < 128; n += 4) {
        float4 cv[4], hv[4];
        #pragma unroll
        for (int i = 0; i < 4; i++) cv[i] = *(const float4*)&sCt[(tB + i) * 132 + n];
        #pragma unroll
        for (int j = 0; j < 4; j++) hv[j] = *(const float4*)&sH[(pB + j) * 132 + n];
        #pragma unroll
        for (int i = 0; i < 4; i++)
            #pragma unroll
            for (int j = 0; j < 4; j++) {
                acc[i][j] = fmaf(cv[i].x, hv[j].x, acc[i][j]);
                acc[i][j] = fmaf(cv[i].y, hv[j].y, acc[i][j]);
                acc[i][j] = fmaf(cv[i].z, hv[j].z, acc[i][j]);
                acc[i][j] = fmaf(cv[i].w, hv[j].w, acc[i][j]);
            }
    }

    #pragma unroll
    for (int i = 0; i < 4; i++) {
        long yoff = (rowbase + tB + i) * DI + hh * HD + pB;
        float pm = sP[tB + i];
        float4 yv = *(const float4*)&yssm[yoff];
        yv.x += pm * acc[i][0];
        yv.y += pm * acc[i][1];
        yv.z += pm * acc[i][2];
        yv.w += pm * acc[i][3];
        *(float4*)&yssm[yoff] = yv;
    }
}

// ---------------------------------------------------------------------------
// Gating: y = (y_ssm + D[h]*x_conv) * silu(z), output bf16 for out_proj MFMA
// ---------------------------------------------------------------------------
__global__ __launch_bounds__(256) void k_gate(const float* __restrict__ proj,
                                              const float* __restrict__ xconv,
                                              const float* __restrict__ Dv,
                                              const float* __restrict__ y,
                                              __bf16* __restrict__ yg) {
    int idx = blockIdx.x * 256 + threadIdx.x;
    int c = idx & (DI - 1);
    int row = idx >> 11;
    int hh = c >> 6;
    float yv = y[idx] + Dv[hh] * xconv[idx];
    float z = proj[(long)row * PS + c];
    yg[idx] = (__bf16)(yv * (z / (1.0f + expf(-z))));
}

// ---------------------------------------------------------------------------
extern "C" void kernel_launch(void* const* d_in, const int* in_sizes, int n_in,
                              void* d_out, int out_size, void* d_ws, size_t ws_size,
                              hipStream_t stream) {
    const float* x       = (const float*)d_in[0];
    const float* norm_w  = (const float*)d_in[1];
    const float* Wp      = (const float*)d_in[2];   // (4384, 1024)
    const float* cw      = (const float*)d_in[3];
    const float* cb      = (const float*)d_in[4];
    const float* A_log   = (const float*)d_in[5];
    const float* Dv      = (const float*)d_in[6];
    const float* dt_bias = (const float*)d_in[7];
    const float* Wo      = (const float*)d_in[8];   // (1024, 2048)
    float* out = (float*)d_out;

    // workspace layout (floats); U is time-multiplexed:
    //   phase 1: xnb (2,097,152 fl) + Wpb (2,244,608 fl)
    //   phase 2: Sloc (16,777,216 fl)
    //   phase 3: Wob (1,048,576 fl = 2,097,152 bf16) + ybb (2,097,152 fl)
    float* ws    = (float*)d_ws;
    float* proj  = ws;                        // 4096*4480 = 18,350,080
    float* xconv = proj  + 18350080;          //  8,388,608
    float* dtb   = xconv +  8388608;          //    131,072
    float* dAb   = dtb   +   131072;          //    131,072
    float* clog  = dAb   +   131072;          //    131,072
    float* yb    = clog  +   131072;          //  8,388,608
    float* U     = yb    +  8388608;          // 16,777,216
    // total 52,297,728 floats = 209.2 MB

    __bf16* xnb  = (__bf16*)U;
    __bf16* Wpb  = (__bf16*)(U + 2097152);
    float*  Sloc = U;
    __bf16* Wob  = (__bf16*)U;
    __bf16* ybb  = (__bf16*)(U + 1048576);   // FIX: was U+524288, inside Wob

    // phase 1: input prep + in_proj GEMM
    k_f2b<<<4384, 256, 0, stream>>>(Wp, Wpb, (DP * DM) / 4);
    k_rmsnorm<<<M_ROWS, 256, 0, stream>>>(x, norm_w, xnb);
    {
        dim3 g(PS / 128, M_ROWS / 128);
        k_gemm_bf<<<g, 256, 0, stream>>>(xnb, Wpb, nullptr, proj, DP, DM, PS);
    }

    k_conv<<<(M_ROWS * DI) / 256, 256, 0, stream>>>(proj, cw, cb, xconv);
    k_dt<<<(M_ROWS * NH) / 256, 256, 0, stream>>>(proj, A_log, dt_bias, dtb, dAb);
    k_cumlog<<<8, 256, 0, stream>>>(dtb, A_log, clog);

    // phase 2: segmented scan (Sloc overwrites xnb/Wpb — both dead)
    k_scan_local<<<B_SZ * NH * NC * 2, 256, 0, stream>>>(proj, xconv, dtb, dAb, yb, Sloc);
    k_carry<<<(B_SZ * NH * HD * DS) / 256, 256, 0, stream>>>(Sloc, clog);
    k_fix<<<B_SZ * NH * NC, 256, 0, stream>>>(proj, Sloc, clog, yb);

    // phase 3: gate + out_proj (Wob/ybb overwrite Sloc — dead)
    k_f2b<<<2048, 256, 0, stream>>>(Wo, Wob, (DM * DI) / 4);
    k_gate<<<(M_ROWS * DI) / 256, 256, 0, stream>>>(proj, xconv, Dv, yb, ybb);
    {
        dim3 g(DM / 128, M_ROWS / 128);
        k_gemm_bf<<<g, 256, 0, stream>>>(ybb, Wob, x, out, DM, DI, DM);
    }
}

// Round 6
// 418.744 us; speedup vs baseline: 3.6148x; 1.2090x over previous
//
#include <hip/hip_runtime.h>
#include <math.h>

#define B_SZ     2
#define L_SEQ    2048
#define DM       1024      // D_MODEL
#define DP       4384      // D_PROJ (logical)
#define PS       4480      // proj padded stride (35 * 128)
#define DI       2048      // D_INNER
#define NH       32        // N_HEADS
#define HD       64        // HEAD_DIM
#define DS       128       // D_STATE
#define M_ROWS   (B_SZ * L_SEQ)   // 4096
#define QCH      64        // scan chunk length
#define NC       (L_SEQ / QCH)    // 32 chunks

typedef __bf16 bf16x8 __attribute__((ext_vector_type(8)));
typedef __bf16 bf16x4 __attribute__((ext_vector_type(4)));
typedef float  f32x4  __attribute__((ext_vector_type(4)));

// ---------------------------------------------------------------------------
// fp32 -> bf16 conversion (weights)
// ---------------------------------------------------------------------------
__global__ __launch_bounds__(256) void k_f2b(const float* __restrict__ src,
                                             __bf16* __restrict__ dst, int n4) {
    int i = blockIdx.x * 256 + threadIdx.x;
    if (i < n4) {
        float4 v = ((const float4*)src)[i];
        bf16x4 o = { (__bf16)v.x, (__bf16)v.y, (__bf16)v.z, (__bf16)v.w };
        ((bf16x4*)dst)[i] = o;
    }
}

// ---------------------------------------------------------------------------
// RMSNorm: one block per row of 1024, float4 in, bf16 out
// ---------------------------------------------------------------------------
__global__ __launch_bounds__(256) void k_rmsnorm(const float* __restrict__ x,
                                                 const float* __restrict__ w,
                                                 __bf16* __restrict__ xn) {
    int row = blockIdx.x;
    int tid = threadIdx.x;
    const float4* x4 = (const float4*)(x + (long)row * DM);
    float4 v = x4[tid];
    float ss = v.x * v.x + v.y * v.y + v.z * v.z + v.w * v.w;
    #pragma unroll
    for (int off = 32; off > 0; off >>= 1) ss += __shfl_xor(ss, off, 64);
    __shared__ float sred[4];
    if ((tid & 63) == 0) sred[tid >> 6] = ss;
    __syncthreads();
    float tot = sred[0] + sred[1] + sred[2] + sred[3];
    float scale = rsqrtf(tot * (1.0f / (float)DM) + 1e-6f);
    const float4* w4 = (const float4*)w;
    float4 wv = w4[tid];
    bf16x4 o = { (__bf16)(v.x * scale * wv.x), (__bf16)(v.y * scale * wv.y),
                 (__bf16)(v.z * scale * wv.z), (__bf16)(v.w * scale * wv.w) };
    ((bf16x4*)(xn + (long)row * DM))[tid] = o;
}

// ---------------------------------------------------------------------------
// bf16 MFMA GEMM (m93 structure, register staging): C = A @ W^T (+resid).
// 128x128 tile, BK=32, 4 waves, 4x4 mfma_f32_16x16x32_bf16. (HW-verified R5)
// ---------------------------------------------------------------------------
__global__ __launch_bounds__(256) void k_gemm_bf(const __bf16* __restrict__ A,
                                                 const __bf16* __restrict__ W,
                                                 const float* __restrict__ resid,
                                                 float* __restrict__ C,
                                                 int Nw, int K, int ldc) {
    __shared__ __align__(16) __bf16 As[128 * 40];
    __shared__ __align__(16) __bf16 Bs[128 * 40];
    int t = threadIdx.x;
    int bm = blockIdx.y * 128, bn = blockIdx.x * 128;

    int r0 = t >> 2;
    int c0 = (t & 3) * 8;
    int r1 = r0 + 64;
    const __bf16* Ag0 = A + (long)(bm + r0) * K + c0;
    const __bf16* Ag1 = A + (long)(bm + r1) * K + c0;
    int br0 = bn + r0; if (br0 >= Nw) br0 = Nw - 1;
    int br1 = bn + r1; if (br1 >= Nw) br1 = Nw - 1;
    const __bf16* Wg0 = W + (long)br0 * K + c0;
    const __bf16* Wg1 = W + (long)br1 * K + c0;
    __bf16* Al0 = As + r0 * 40 + c0;
    __bf16* Al1 = As + r1 * 40 + c0;
    __bf16* Bl0 = Bs + r0 * 40 + c0;
    __bf16* Bl1 = Bs + r1 * 40 + c0;

    int lane = t & 63, w = t >> 6;
    int wm = (w & 1) * 64, wn = (w >> 1) * 64;
    int ln = lane & 15;
    int kc = (lane >> 4) * 8;
    const __bf16* Ar = As + (wm + ln) * 40 + kc;
    const __bf16* Br = Bs + (wn + ln) * 40 + kc;

    f32x4 acc[4][4] = {};

    for (int k0 = 0; k0 < K; k0 += 32) {
        bf16x8 a0 = *(const bf16x8*)(Ag0 + k0);
        bf16x8 a1 = *(const bf16x8*)(Ag1 + k0);
        bf16x8 b0 = *(const bf16x8*)(Wg0 + k0);
        bf16x8 b1 = *(const bf16x8*)(Wg1 + k0);
        __syncthreads();
        *(bf16x8*)Al0 = a0;
        *(bf16x8*)Al1 = a1;
        *(bf16x8*)Bl0 = b0;
        *(bf16x8*)Bl1 = b1;
        __syncthreads();

        bf16x8 af[4], bfr[4];
        #pragma unroll
        for (int i = 0; i < 4; i++) af[i]  = *(const bf16x8*)(Ar + i * 16 * 40);
        #pragma unroll
        for (int j = 0; j < 4; j++) bfr[j] = *(const bf16x8*)(Br + j * 16 * 40);
        #pragma unroll
        for (int i = 0; i < 4; i++)
            #pragma unroll
            for (int j = 0; j < 4; j++)
                acc[i][j] = __builtin_amdgcn_mfma_f32_16x16x32_bf16(
                                af[i], bfr[j], acc[i][j], 0, 0, 0);
    }

    #pragma unroll
    for (int i = 0; i < 4; i++) {
        #pragma unroll
        for (int r = 0; r < 4; r++) {
            int m = bm + wm + i * 16 + (lane >> 4) * 4 + r;
            long off = (long)m * ldc + bn + wn + ln;
            #pragma unroll
            for (int j = 0; j < 4; j++) {
                float v = acc[i][j][r];
                if (resid != nullptr) v += resid[off + j * 16];
                C[off + j * 16] = v;
            }
        }
    }
}

// ---------------------------------------------------------------------------
// Depthwise causal conv K=4 + bias + SiLU
// ---------------------------------------------------------------------------
__global__ __launch_bounds__(256) void k_conv(const float* __restrict__ proj,
                                              const float* __restrict__ cw,
                                              const float* __restrict__ cb,
                                              float* __restrict__ xconv) {
    int idx = blockIdx.x * 256 + threadIdx.x;
    int c = idx & (DI - 1);
    int t = (idx >> 11) & (L_SEQ - 1);
    int b = idx >> 22;
    const float* base = proj + (long)(b * L_SEQ) * PS + DI + c;
    float acc = cb[c];
    #pragma unroll
    for (int j = 0; j < 4; j++) {
        int tau = t - 3 + j;
        if (tau >= 0) acc = fmaf(cw[c * 4 + j], base[(long)tau * PS], acc);
    }
    xconv[idx] = acc / (1.0f + expf(-acc));
}

// ---------------------------------------------------------------------------
// dt = softplus(dt_raw + dt_bias)
// ---------------------------------------------------------------------------
__global__ __launch_bounds__(256) void k_dt(const float* __restrict__ proj,
                                            const float* __restrict__ dt_bias,
                                            float* __restrict__ dtb) {
    int idx = blockIdx.x * 256 + threadIdx.x;
    int hh = idx & 31;
    int row = idx >> 5;
    float xr = proj[(long)row * PS + 4352 + hh] + dt_bias[hh];
    dtb[idx] = (xr > 20.0f) ? xr : log1pf(expf(xr));
}

// ---------------------------------------------------------------------------
// Per-chunk cumulative log-decay
// ---------------------------------------------------------------------------
__global__ __launch_bounds__(256) void k_cumlog(const float* __restrict__ dtb,
                                                const float* __restrict__ A_log,
                                                float* __restrict__ clog) {
    int idx = blockIdx.x * 256 + threadIdx.x;   // < 2048
    int c  = idx & 31;
    int hh = (idx >> 5) & 31;
    int b  = idx >> 10;
    float la = -expf(A_log[hh]);
    long base = ((long)b * L_SEQ + c * QCH) * NH + hh;
    float run = 0.0f;
    for (int t = 0; t < QCH; t++) {
        run += la * dtb[base + (long)t * NH];
        clog[base + (long)t * NH] = run;
    }
}

// ---------------------------------------------------------------------------
// Phase A (MFMA): per (b,h,c): G=C@B^T; M=causal-decay*G; Y_loc=M@DTX;
// S_loc = (w.*DTX)^T-accumulated = sum_s w_s*dtx[s,p]*B[s,n].
// Fragment layouts: A-op lane m=lane&15,k=(lane>>4)*8+j; C/D col=lane&15,
// row=(lane>>4)*4+reg (both HW-verified via k_gemm_bf this session).
// ---------------------------------------------------------------------------
__global__ __launch_bounds__(256) void k_chunk(const float* __restrict__ proj,
                                               const float* __restrict__ xconv,
                                               const float* __restrict__ dtb,
                                               const float* __restrict__ clog,
                                               float* __restrict__ yssm,
                                               float* __restrict__ Sloc) {
    int blk = blockIdx.x;
    int c  = blk & 31;
    int hh = (blk >> 5) & 31;
    int b  = blk >> 10;
    int tid = threadIdx.x;
    long rowbase = (long)b * L_SEQ + c * QCH;

    __shared__ __align__(16) __bf16 sB[64 * 136];   // B_chunk [s][n]
    __shared__ __align__(16) __bf16 sU[128 * 72];   // phase1: C [t][n] str 136; phase2: B^T [n][s] str 72
    __shared__ __align__(16) __bf16 sXT[64 * 72];   // dtx^T [p][s]
    __shared__ __align__(16) __bf16 sM[64 * 72];    // M [t][s]
    __shared__ float sclog[64];
    __shared__ float sw[64];

    // ---- stage B, C (fp32->bf16), DTX^T, clog ----
    #pragma unroll
    for (int j = 0; j < 8; j++) {
        int off = j * 256 + tid;          // float4 index, 2048 = 64 rows * 32
        int t  = off >> 5;
        int n4 = (off & 31) * 4;
        const float* pr = proj + (rowbase + t) * PS;
        float4 bv = *(const float4*)(pr + 4096 + n4);
        float4 cv = *(const float4*)(pr + 4224 + n4);
        bf16x4 bb = {(__bf16)bv.x, (__bf16)bv.y, (__bf16)bv.z, (__bf16)bv.w};
        bf16x4 cc = {(__bf16)cv.x, (__bf16)cv.y, (__bf16)cv.z, (__bf16)cv.w};
        *(bf16x4*)&sB[t * 136 + n4] = bb;
        *(bf16x4*)&sU[t * 136 + n4] = cc;
    }
    #pragma unroll
    for (int j = 0; j < 4; j++) {
        int off = j * 256 + tid;          // 1024 = 64 s-rows * 16 float4
        int s  = off >> 4;
        int p4 = (off & 15) * 4;
        long rr = rowbase + s;
        float dtv = dtb[rr * NH + hh];
        float4 xv = *(const float4*)(xconv + rr * DI + hh * HD + p4);
        sXT[(p4 + 0) * 72 + s] = (__bf16)(dtv * xv.x);
        sXT[(p4 + 1) * 72 + s] = (__bf16)(dtv * xv.y);
        sXT[(p4 + 2) * 72 + s] = (__bf16)(dtv * xv.z);
        sXT[(p4 + 3) * 72 + s] = (__bf16)(dtv * xv.w);
    }
    if (tid < 64) sclog[tid] = clog[(rowbase + tid) * NH + hh];
    __syncthreads();
    if (tid < 64) sw[tid] = expf(sclog[63] - sclog[tid]);

    int lane = tid & 63, w = tid >> 6;
    int ln = lane & 15;
    int quad = lane >> 4;
    int kc = quad * 8;

    // ---- G = C @ B^T : wave w does t-rows [16w,16w+16), all 64 s-cols ----
    bf16x8 caf[4];
    #pragma unroll
    for (int k0 = 0; k0 < 4; k0++)
        caf[k0] = *(const bf16x8*)&sU[(16 * w + ln) * 136 + kc + k0 * 32];
    f32x4 g[4] = {};
    #pragma unroll
    for (int j = 0; j < 4; j++)
        #pragma unroll
        for (int k0 = 0; k0 < 4; k0++) {
            bf16x8 bf_ = *(const bf16x8*)&sB[(16 * j + ln) * 136 + kc + k0 * 32];
            g[j] = __builtin_amdgcn_mfma_f32_16x16x32_bf16(caf[k0], bf_, g[j], 0, 0, 0);
        }

    // ---- M[t,s] = (s<=t) ? exp(clog_t - clog_s) * G : 0 ; write to sM ----
    {
        int trow = 16 * w + quad * 4;
        #pragma unroll
        for (int r = 0; r < 4; r++) {
            int t = trow + r;
            float ct = sclog[t];
            #pragma unroll
            for (int j = 0; j < 4; j++) {
                int s = 16 * j + ln;
                float v = (s <= t) ? g[j][r] * expf(ct - sclog[s]) : 0.0f;
                sM[t * 72 + s] = (__bf16)v;
            }
        }
    }
    __syncthreads();   // sM complete; sU (C) now dead

    // ---- transpose sB -> sU as B^T [n][s] (stride 72) ----
    #pragma unroll
    for (int j = 0; j < 4; j++) {
        int s  = tid & 63;
        int n8 = (j * 4 + (tid >> 6)) * 8;
        bf16x8 v = *(const bf16x8*)&sB[s * 136 + n8];
        #pragma unroll
        for (int k = 0; k < 8; k++) sU[(n8 + k) * 72 + s] = v[k];
    }

    // ---- Y_loc = M @ DTX : wave w does t-rows [16w,16w+16), 64 p-cols ----
    {
        bf16x8 maf[2];
        #pragma unroll
        for (int k0 = 0; k0 < 2; k0++)
            maf[k0] = *(const bf16x8*)&sM[(16 * w + ln) * 72 + kc + k0 * 32];
        f32x4 y[4] = {};
        #pragma unroll
        for (int j = 0; j < 4; j++)
            #pragma unroll
            for (int k0 = 0; k0 < 2; k0++) {
                bf16x8 xf = *(const bf16x8*)&sXT[(16 * j + ln) * 72 + kc + k0 * 32];
                y[j] = __builtin_amdgcn_mfma_f32_16x16x32_bf16(maf[k0], xf, y[j], 0, 0, 0);
            }
        #pragma unroll
        for (int j = 0; j < 4; j++)
            #pragma unroll
            for (int r = 0; r < 4; r++) {
                int t = 16 * w + quad * 4 + r;
                int p = 16 * j + ln;
                yssm[(rowbase + t) * DI + hh * HD + p] = y[j][r];
            }
    }
    __syncthreads();   // sU (B^T) complete

    // ---- S_loc[p,n] = sum_s w_s * dtx[s,p] * B[s,n] ----
    {
        bf16x8 xaf[2];
        #pragma unroll
        for (int k0 = 0; k0 < 2; k0++) {
            bf16x8 raw = *(const bf16x8*)&sXT[(16 * w + ln) * 72 + kc + k0 * 32];
            bf16x8 sc;
            #pragma unroll
            for (int jj = 0; jj < 8; jj++) {
                int s = kc + k0 * 32 + jj;
                sc[jj] = (__bf16)((float)raw[jj] * sw[s]);
            }
            xaf[k0] = sc;
        }
        f32x4 sacc[8] = {};
        #pragma unroll
        for (int j = 0; j < 8; j++)
            #pragma unroll
            for (int k0 = 0; k0 < 2; k0++) {
                bf16x8 btf = *(const bf16x8*)&sU[(16 * j + ln) * 72 + kc + k0 * 32];
                sacc[j] = __builtin_amdgcn_mfma_f32_16x16x32_bf16(xaf[k0], btf, sacc[j], 0, 0, 0);
            }
        long sbase = ((long)(b * NH + hh) * NC + c) * (HD * DS);
        #pragma unroll
        for (int j = 0; j < 8; j++)
            #pragma unroll
            for (int r = 0; r < 4; r++) {
                int p = 16 * w + quad * 4 + r;
                int n = 16 * j + ln;
                Sloc[sbase + p * DS + n] = sacc[j][r];
            }
    }
}

// ---------------------------------------------------------------------------
// Phase B: sequential carry over chunks (in-place: S_c -> H_in(c))
// ---------------------------------------------------------------------------
__global__ __launch_bounds__(256) void k_carry(float* __restrict__ Sloc,
                                               const float* __restrict__ clog) {
    int idx = blockIdx.x * 256 + threadIdx.x;   // < 524288
    int n  = idx & 127;
    int p  = (idx >> 7) & 63;
    int hh = (idx >> 13) & 31;
    int b  = idx >> 18;
    long base = ((long)(b * NH + hh) * NC) * (HD * DS) + p * DS + n;
    float T = 0.0f;
    for (int c = 0; c < NC; c++) {
        float lam = expf(clog[((long)b * L_SEQ + c * QCH + QCH - 1) * NH + hh]);
        long a = base + (long)c * (HD * DS);
        float S = Sloc[a];
        Sloc[a] = T;
        T = fmaf(T, lam, S);
    }
}

// ---------------------------------------------------------------------------
// Phase C: inter-chunk correction y += exp(clog_t) * (C_t . Hin[p,:])
// ---------------------------------------------------------------------------
__global__ __launch_bounds__(256, 2) void k_fix(const float* __restrict__ proj,
                                                const float* __restrict__ Sloc,
                                                const float* __restrict__ clog,
                                                float* __restrict__ yssm) {
    int blk = blockIdx.x;
    int c  = blk & 31;
    int hh = (blk >> 5) & 31;
    int b  = blk >> 10;

    __shared__ float sH[64 * 132];
    __shared__ float sCt[64 * 132];
    __shared__ float sP[64];

    int tid = threadIdx.x;
    long hbase = ((long)(b * NH + hh) * NC + c) * (HD * DS);
    long rowbase = (long)b * L_SEQ + c * QCH;

    #pragma unroll
    for (int j = 0; j < 8; j++) {
        int off = j * 1024 + tid * 4;
        int p = off >> 7, n = off & 127;
        *(float4*)&sH[p * 132 + n] = *(const float4*)&Sloc[hbase + off];
    }
    #pragma unroll
    for (int j = 0; j < 8; j++) {
        int off = j * 1024 + tid * 4;
        int t = off >> 7, n = off & 127;
        *(float4*)&sCt[t * 132 + n] = *(const float4*)&proj[(rowbase + t) * PS + 4224 + n];
    }
    if (tid < 64) sP[tid] = expf(clog[(rowbase + tid) * NH + hh]);
    __syncthreads();

    int tx = tid & 15, ty = tid >> 4;
    int pB = tx * 4, tB = ty * 4;
    float acc[4][4] = {};

    for (int n = 0; n < 128; n += 4) {
        float4 cv[4], hv[4];
        #pragma unroll
        for (int i = 0; i < 4; i++) cv[i] = *(const float4*)&sCt[(tB + i) * 132 + n];
        #pragma unroll
        for (int j = 0; j < 4; j++) hv[j] = *(const float4*)&sH[(pB + j) * 132 + n];
        #pragma unroll
        for (int i = 0; i < 4; i++)
            #pragma unroll
            for (int j = 0; j < 4; j++) {
                acc[i][j] = fmaf(cv[i].x, hv[j].x, acc[i][j]);
                acc[i][j] = fmaf(cv[i].y, hv[j].y, acc[i][j]);
                acc[i][j] = fmaf(cv[i].z, hv[j].z, acc[i][j]);
                acc[i][j] = fmaf(cv[i].w, hv[j].w, acc[i][j]);
            }
    }

    #pragma unroll
    for (int i = 0; i < 4; i++) {
        long yoff = (rowbase + tB + i) * DI + hh * HD + pB;
        float pm = sP[tB + i];
        float4 yv = *(const float4*)&yssm[yoff];
        yv.x += pm * acc[i][0];
        yv.y += pm * acc[i][1];
        yv.z += pm * acc[i][2];
        yv.w += pm * acc[i][3];
        *(float4*)&yssm[yoff] = yv;
    }
}

// ---------------------------------------------------------------------------
// Gating: y = (y_ssm + D[h]*x_conv) * silu(z), bf16 out
// ---------------------------------------------------------------------------
__global__ __launch_bounds__(256) void k_gate(const float* __restrict__ proj,
                                              const float* __restrict__ xconv,
                                              const float* __restrict__ Dv,
                                              const float* __restrict__ y,
                                              __bf16* __restrict__ yg) {
    int idx = blockIdx.x * 256 + threadIdx.x;
    int c = idx & (DI - 1);
    int row = idx >> 11;
    int hh = c >> 6;
    float yv = y[idx] + Dv[hh] * xconv[idx];
    float z = proj[(long)row * PS + c];
    yg[idx] = (__bf16)(yv * (z / (1.0f + expf(-z))));
}

// ---------------------------------------------------------------------------
extern "C" void kernel_launch(void* const* d_in, const int* in_sizes, int n_in,
                              void* d_out, int out_size, void* d_ws, size_t ws_size,
                              hipStream_t stream) {
    const float* x       = (const float*)d_in[0];
    const float* norm_w  = (const float*)d_in[1];
    const float* Wp      = (const float*)d_in[2];   // (4384, 1024)
    const float* cw      = (const float*)d_in[3];
    const float* cb      = (const float*)d_in[4];
    const float* A_log   = (const float*)d_in[5];
    const float* Dv      = (const float*)d_in[6];
    const float* dt_bias = (const float*)d_in[7];
    const float* Wo      = (const float*)d_in[8];   // (1024, 2048)
    float* out = (float*)d_out;

    float* ws    = (float*)d_ws;
    float* proj  = ws;                        // 4096*4480 = 18,350,080
    float* xconv = proj  + 18350080;          //  8,388,608
    float* dtb   = xconv +  8388608;          //    131,072
    float* dAb   = dtb   +   131072;          //    131,072 (unused, layout kept)
    float* clog  = dAb   +   131072;          //    131,072
    float* yb    = clog  +   131072;          //  8,388,608
    float* U     = yb    +  8388608;          // 16,777,216
    // total 52,297,728 floats = 209.2 MB

    __bf16* xnb  = (__bf16*)U;
    __bf16* Wpb  = (__bf16*)(U + 2097152);
    float*  Sloc = U;
    __bf16* Wob  = (__bf16*)U;                // 1,048,576 floats of space
    __bf16* ybb  = (__bf16*)(U + 1048576);

    // phase 1: input prep + in_proj GEMM
    k_f2b<<<4384, 256, 0, stream>>>(Wp, Wpb, (DP * DM) / 4);
    k_rmsnorm<<<M_ROWS, 256, 0, stream>>>(x, norm_w, xnb);
    {
        dim3 g(PS / 128, M_ROWS / 128);
        k_gemm_bf<<<g, 256, 0, stream>>>(xnb, Wpb, nullptr, proj, DP, DM, PS);
    }

    k_conv<<<(M_ROWS * DI) / 256, 256, 0, stream>>>(proj, cw, cb, xconv);
    k_dt<<<(M_ROWS * NH) / 256, 256, 0, stream>>>(proj, dt_bias, dtb);
    k_cumlog<<<8, 256, 0, stream>>>(dtb, A_log, clog);

    // phase 2: chunked scan via MFMA (Sloc overwrites xnb/Wpb — dead)
    k_chunk<<<B_SZ * NH * NC, 256, 0, stream>>>(proj, xconv, dtb, clog, yb, Sloc);
    k_carry<<<(B_SZ * NH * HD * DS) / 256, 256, 0, stream>>>(Sloc, clog);
    k_fix<<<B_SZ * NH * NC, 256, 0, stream>>>(proj, Sloc, clog, yb);

    // phase 3: gate + out_proj (Wob/ybb overwrite Sloc — dead)
    k_f2b<<<2048, 256, 0, stream>>>(Wo, Wob, (DM * DI) / 4);
    k_gate<<<(M_ROWS * DI) / 256, 256, 0, stream>>>(proj, xconv, Dv, yb, ybb);
    {
        dim3 g(DM / 128, M_ROWS / 128);
        k_gemm_bf<<<g, 256, 0, stream>>>(ybb, Wob, x, out, DM, DI, DM);
    }
}

// Round 7
// 398.948 us; speedup vs baseline: 3.7942x; 1.0496x over previous
//
#include <hip/hip_runtime.h>
#include <math.h>

#define B_SZ     2
#define L_SEQ    2048
#define DM       1024      // D_MODEL
#define DP       4384      // D_PROJ (logical)
#define PS       4480      // proj padded stride (35 * 128)
#define DI       2048      // D_INNER
#define NH       32        // N_HEADS
#define HD       64        // HEAD_DIM
#define DS       128       // D_STATE
#define M_ROWS   (B_SZ * L_SEQ)   // 4096
#define QCH      64        // scan chunk length
#define NC       (L_SEQ / QCH)    // 32 chunks

typedef __bf16 bf16x8 __attribute__((ext_vector_type(8)));
typedef __bf16 bf16x4 __attribute__((ext_vector_type(4)));
typedef float  f32x4  __attribute__((ext_vector_type(4)));

__device__ __forceinline__ void load16(const void* g, void* l) {
    __builtin_amdgcn_global_load_lds(
        (const __attribute__((address_space(1))) unsigned int*)g,
        (__attribute__((address_space(3))) unsigned int*)l, 16, 0, 0);
}

// ---------------------------------------------------------------------------
// fp32 -> bf16 conversion (weights)
// ---------------------------------------------------------------------------
__global__ __launch_bounds__(256) void k_f2b(const float* __restrict__ src,
                                             __bf16* __restrict__ dst, int n4) {
    int i = blockIdx.x * 256 + threadIdx.x;
    if (i < n4) {
        float4 v = ((const float4*)src)[i];
        bf16x4 o = { (__bf16)v.x, (__bf16)v.y, (__bf16)v.z, (__bf16)v.w };
        ((bf16x4*)dst)[i] = o;
    }
}

// ---------------------------------------------------------------------------
// RMSNorm: one block per row of 1024, float4 in, bf16 out
// ---------------------------------------------------------------------------
__global__ __launch_bounds__(256) void k_rmsnorm(const float* __restrict__ x,
                                                 const float* __restrict__ w,
                                                 __bf16* __restrict__ xn) {
    int row = blockIdx.x;
    int tid = threadIdx.x;
    const float4* x4 = (const float4*)(x + (long)row * DM);
    float4 v = x4[tid];
    float ss = v.x * v.x + v.y * v.y + v.z * v.z + v.w * v.w;
    #pragma unroll
    for (int off = 32; off > 0; off >>= 1) ss += __shfl_xor(ss, off, 64);
    __shared__ float sred[4];
    if ((tid & 63) == 0) sred[tid >> 6] = ss;
    __syncthreads();
    float tot = sred[0] + sred[1] + sred[2] + sred[3];
    float scale = rsqrtf(tot * (1.0f / (float)DM) + 1e-6f);
    const float4* w4 = (const float4*)w;
    float4 wv = w4[tid];
    bf16x4 o = { (__bf16)(v.x * scale * wv.x), (__bf16)(v.y * scale * wv.y),
                 (__bf16)(v.z * scale * wv.z), (__bf16)(v.w * scale * wv.w) };
    ((bf16x4*)(xn + (long)row * DM))[tid] = o;
}

// ---------------------------------------------------------------------------
// bf16 MFMA GEMM (m97 structure): C = A @ W^T (+resid). 128x128 tile, BK=32,
// global_load_lds width=16 staging with XOR k-chunk swizzle (this exact
// staging verified: R3 output bit-identical to R4's verified register path).
// ---------------------------------------------------------------------------
__global__ __launch_bounds__(256) void k_gemm_bf(const __bf16* __restrict__ A,
                                                 const __bf16* __restrict__ W,
                                                 const float* __restrict__ resid,
                                                 float* __restrict__ C,
                                                 int Nw, int K, int ldc) {
    __shared__ __align__(16) __bf16 As[128 * 32];
    __shared__ __align__(16) __bf16 Bs[128 * 32];
    int t = threadIdx.x;
    int bm = blockIdx.y * 128, bn = blockIdx.x * 128;

    // staging: thread t loads 16B to LDS offset t*16B (wave-contiguous)
    int srow = t >> 2;                               // 0..63
    int klog = ((t & 3) ^ (srow & 3)) << 3;          // swizzled k-chunk
    const __bf16* Ag0 = A + (long)(bm + srow) * K + klog;
    const __bf16* Ag1 = Ag0 + 64 * (long)K;
    int br0 = bn + srow;      if (br0 >= Nw) br0 = Nw - 1;
    int br1 = bn + srow + 64; if (br1 >= Nw) br1 = Nw - 1;
    const __bf16* Wg0 = W + (long)br0 * K + klog;
    const __bf16* Wg1 = W + (long)br1 * K + klog;
    __bf16* Al0 = As + t * 8;
    __bf16* Al1 = As + 2048 + t * 8;
    __bf16* Bl0 = Bs + t * 8;
    __bf16* Bl1 = Bs + 2048 + t * 8;

    // compute-side: physical k-chunk = logical quad ^ (row&3)
    int lane = t & 63, w = t >> 6;
    int wm = (w & 1) * 64, wn = (w >> 1) * 64;
    int ln = lane & 15;
    int pc = ((lane >> 4) ^ (lane & 3)) << 3;
    const __bf16* Ar = As + (wm + ln) * 32 + pc;
    const __bf16* Br = Bs + (wn + ln) * 32 + pc;

    f32x4 acc[4][4] = {};

    for (int k0 = 0; k0 < K; k0 += 32) {
        __syncthreads();
        load16(Ag0 + k0, Al0);
        load16(Ag1 + k0, Al1);
        load16(Wg0 + k0, Bl0);
        load16(Wg1 + k0, Bl1);
        __syncthreads();

        bf16x8 af[4], bfr[4];
        #pragma unroll
        for (int i = 0; i < 4; i++) af[i]  = *(const bf16x8*)(Ar + i * 512);
        #pragma unroll
        for (int j = 0; j < 4; j++) bfr[j] = *(const bf16x8*)(Br + j * 512);
        #pragma unroll
        for (int i = 0; i < 4; i++)
            #pragma unroll
            for (int j = 0; j < 4; j++)
                acc[i][j] = __builtin_amdgcn_mfma_f32_16x16x32_bf16(
                                af[i], bfr[j], acc[i][j], 0, 0, 0);
    }

    // epilogue: C/D layout col=lane&15, row=(lane>>4)*4+reg
    #pragma unroll
    for (int i = 0; i < 4; i++) {
        #pragma unroll
        for (int r = 0; r < 4; r++) {
            int m = bm + wm + i * 16 + (lane >> 4) * 4 + r;
            long off = (long)m * ldc + bn + wn + ln;
            #pragma unroll
            for (int j = 0; j < 4; j++) {
                float v = acc[i][j][r];
                if (resid != nullptr) v += resid[off + j * 16];
                C[off + j * 16] = v;
            }
        }
    }
}

// ---------------------------------------------------------------------------
// Depthwise causal conv K=4 + bias + SiLU
// ---------------------------------------------------------------------------
__global__ __launch_bounds__(256) void k_conv(const float* __restrict__ proj,
                                              const float* __restrict__ cw,
                                              const float* __restrict__ cb,
                                              float* __restrict__ xconv) {
    int idx = blockIdx.x * 256 + threadIdx.x;
    int c = idx & (DI - 1);
    int t = (idx >> 11) & (L_SEQ - 1);
    int b = idx >> 22;
    const float* base = proj + (long)(b * L_SEQ) * PS + DI + c;
    float acc = cb[c];
    #pragma unroll
    for (int j = 0; j < 4; j++) {
        int tau = t - 3 + j;
        if (tau >= 0) acc = fmaf(cw[c * 4 + j], base[(long)tau * PS], acc);
    }
    xconv[idx] = acc / (1.0f + expf(-acc));
}

// ---------------------------------------------------------------------------
// Phase A (MFMA) with fused dt/cumlog: per (b,h,c):
//   dt = softplus(dt_raw + bias); clog = inclusive-scan(-exp(A_log)*dt)
//   G=C@B^T; M=causal-decay*G; Y_loc=M@DTX; S_loc=sum_s w_s*dtx[s,p]*B[s,n]
// clog written to global for k_carry/k_fix.
// ---------------------------------------------------------------------------
__global__ __launch_bounds__(256) void k_chunk(const float* __restrict__ proj,
                                               const float* __restrict__ xconv,
                                               const float* __restrict__ A_log,
                                               const float* __restrict__ dt_bias,
                                               float* __restrict__ clog,
                                               float* __restrict__ yssm,
                                               float* __restrict__ Sloc) {
    int blk = blockIdx.x;
    int c  = blk & 31;
    int hh = (blk >> 5) & 31;
    int b  = blk >> 10;
    int tid = threadIdx.x;
    long rowbase = (long)b * L_SEQ + c * QCH;

    __shared__ __align__(16) __bf16 sB[64 * 136];   // B_chunk [s][n]
    __shared__ __align__(16) __bf16 sU[128 * 72];   // phase1: C [t][n] str136; phase2: B^T [n][s] str72
    __shared__ __align__(16) __bf16 sXT[64 * 72];   // dtx^T [p][s]
    __shared__ __align__(16) __bf16 sM[64 * 72];    // M [t][s]
    __shared__ float sclog[64];
    __shared__ float sdt[64];
    __shared__ float sw[64];

    // ---- stage B, C (fp32->bf16) ----
    #pragma unroll
    for (int j = 0; j < 8; j++) {
        int off = j * 256 + tid;          // float4 index, 2048 = 64 rows * 32
        int t  = off >> 5;
        int n4 = (off & 31) * 4;
        const float* pr = proj + (rowbase + t) * PS;
        float4 bv = *(const float4*)(pr + 4096 + n4);
        float4 cv = *(const float4*)(pr + 4224 + n4);
        bf16x4 bb = {(__bf16)bv.x, (__bf16)bv.y, (__bf16)bv.z, (__bf16)bv.w};
        bf16x4 cc = {(__bf16)cv.x, (__bf16)cv.y, (__bf16)cv.z, (__bf16)cv.w};
        *(bf16x4*)&sB[t * 136 + n4] = bb;
        *(bf16x4*)&sU[t * 136 + n4] = cc;
    }

    // ---- wave 0: dt = softplus, clog = inclusive scan, write global ----
    if (tid < 64) {
        float xr = proj[(rowbase + tid) * PS + 4352 + hh] + dt_bias[hh];
        float dt = (xr > 20.0f) ? xr : log1pf(expf(xr));
        float la = -expf(A_log[hh]);
        float v = la * dt;
        #pragma unroll
        for (int off = 1; off < 64; off <<= 1) {
            float u = __shfl_up(v, off, 64);
            if (tid >= off) v += u;
        }
        sdt[tid] = dt;
        sclog[tid] = v;
        clog[(rowbase + tid) * NH + hh] = v;
    }
    __syncthreads();

    // ---- stage DTX^T (needs sdt) + sw ----
    #pragma unroll
    for (int j = 0; j < 4; j++) {
        int off = j * 256 + tid;          // 1024 = 64 s-rows * 16 float4
        int s  = off >> 4;
        int p4 = (off & 15) * 4;
        float dtv = sdt[s];
        float4 xv = *(const float4*)(xconv + (rowbase + s) * DI + hh * HD + p4);
        sXT[(p4 + 0) * 72 + s] = (__bf16)(dtv * xv.x);
        sXT[(p4 + 1) * 72 + s] = (__bf16)(dtv * xv.y);
        sXT[(p4 + 2) * 72 + s] = (__bf16)(dtv * xv.z);
        sXT[(p4 + 3) * 72 + s] = (__bf16)(dtv * xv.w);
    }
    if (tid < 64) sw[tid] = expf(sclog[63] - sclog[tid]);

    int lane = tid & 63, w = tid >> 6;
    int ln = lane & 15;
    int quad = lane >> 4;
    int kc = quad * 8;

    // ---- G = C @ B^T : wave w does t-rows [16w,16w+16), all 64 s-cols ----
    bf16x8 caf[4];
    #pragma unroll
    for (int k0 = 0; k0 < 4; k0++)
        caf[k0] = *(const bf16x8*)&sU[(16 * w + ln) * 136 + kc + k0 * 32];
    f32x4 g[4] = {};
    #pragma unroll
    for (int j = 0; j < 4; j++)
        #pragma unroll
        for (int k0 = 0; k0 < 4; k0++) {
            bf16x8 bf_ = *(const bf16x8*)&sB[(16 * j + ln) * 136 + kc + k0 * 32];
            g[j] = __builtin_amdgcn_mfma_f32_16x16x32_bf16(caf[k0], bf_, g[j], 0, 0, 0);
        }

    // ---- M[t,s] = (s<=t) ? exp(clog_t - clog_s) * G : 0 ----
    {
        int trow = 16 * w + quad * 4;
        #pragma unroll
        for (int r = 0; r < 4; r++) {
            int t = trow + r;
            float ct = sclog[t];
            #pragma unroll
            for (int j = 0; j < 4; j++) {
                int s = 16 * j + ln;
                float v = (s <= t) ? g[j][r] * expf(ct - sclog[s]) : 0.0f;
                sM[t * 72 + s] = (__bf16)v;
            }
        }
    }
    __syncthreads();   // sM + sXT complete; sU (C) now dead

    // ---- transpose sB -> sU as B^T [n][s] (stride 72) ----
    #pragma unroll
    for (int j = 0; j < 4; j++) {
        int s  = tid & 63;
        int n8 = (j * 4 + (tid >> 6)) * 8;
        bf16x8 v = *(const bf16x8*)&sB[s * 136 + n8];
        #pragma unroll
        for (int k = 0; k < 8; k++) sU[(n8 + k) * 72 + s] = v[k];
    }

    // ---- Y_loc = M @ DTX ----
    {
        bf16x8 maf[2];
        #pragma unroll
        for (int k0 = 0; k0 < 2; k0++)
            maf[k0] = *(const bf16x8*)&sM[(16 * w + ln) * 72 + kc + k0 * 32];
        f32x4 y[4] = {};
        #pragma unroll
        for (int j = 0; j < 4; j++)
            #pragma unroll
            for (int k0 = 0; k0 < 2; k0++) {
                bf16x8 xf = *(const bf16x8*)&sXT[(16 * j + ln) * 72 + kc + k0 * 32];
                y[j] = __builtin_amdgcn_mfma_f32_16x16x32_bf16(maf[k0], xf, y[j], 0, 0, 0);
            }
        #pragma unroll
        for (int j = 0; j < 4; j++)
            #pragma unroll
            for (int r = 0; r < 4; r++) {
                int t = 16 * w + quad * 4 + r;
                int p = 16 * j + ln;
                yssm[(rowbase + t) * DI + hh * HD + p] = y[j][r];
            }
    }
    __syncthreads();   // sU (B^T) complete

    // ---- S_loc[p,n] = sum_s w_s * dtx[s,p] * B[s,n] ----
    {
        bf16x8 xaf[2];
        #pragma unroll
        for (int k0 = 0; k0 < 2; k0++) {
            bf16x8 raw = *(const bf16x8*)&sXT[(16 * w + ln) * 72 + kc + k0 * 32];
            bf16x8 sc;
            #pragma unroll
            for (int jj = 0; jj < 8; jj++) {
                int s = kc + k0 * 32 + jj;
                sc[jj] = (__bf16)((float)raw[jj] * sw[s]);
            }
            xaf[k0] = sc;
        }
        f32x4 sacc[8] = {};
        #pragma unroll
        for (int j = 0; j < 8; j++)
            #pragma unroll
            for (int k0 = 0; k0 < 2; k0++) {
                bf16x8 btf = *(const bf16x8*)&sU[(16 * j + ln) * 72 + kc + k0 * 32];
                sacc[j] = __builtin_amdgcn_mfma_f32_16x16x32_bf16(xaf[k0], btf, sacc[j], 0, 0, 0);
            }
        long sbase = ((long)(b * NH + hh) * NC + c) * (HD * DS);
        #pragma unroll
        for (int j = 0; j < 8; j++)
            #pragma unroll
            for (int r = 0; r < 4; r++) {
                int p = 16 * w + quad * 4 + r;
                int n = 16 * j + ln;
                Sloc[sbase + p * DS + n] = sacc[j][r];
            }
    }
}

// ---------------------------------------------------------------------------
// Phase B: sequential carry over chunks (in-place: S_c -> H_in(c))
// ---------------------------------------------------------------------------
__global__ __launch_bounds__(256) void k_carry(float* __restrict__ Sloc,
                                               const float* __restrict__ clog) {
    int idx = blockIdx.x * 256 + threadIdx.x;   // < 524288
    int n  = idx & 127;
    int p  = (idx >> 7) & 63;
    int hh = (idx >> 13) & 31;
    int b  = idx >> 18;
    long base = ((long)(b * NH + hh) * NC) * (HD * DS) + p * DS + n;
    float T = 0.0f;
    for (int c = 0; c < NC; c++) {
        float lam = expf(clog[((long)b * L_SEQ + c * QCH + QCH - 1) * NH + hh]);
        long a = base + (long)c * (HD * DS);
        float S = Sloc[a];
        Sloc[a] = T;
        T = fmaf(T, lam, S);
    }
}

// ---------------------------------------------------------------------------
// Phase C: inter-chunk correction y += exp(clog_t) * (C_t . Hin[p,:])
// ---------------------------------------------------------------------------
__global__ __launch_bounds__(256, 2) void k_fix(const float* __restrict__ proj,
                                                const float* __restrict__ Sloc,
                                                const float* __restrict__ clog,
                                                float* __restrict__ yssm) {
    int blk = blockIdx.x;
    int c  = blk & 31;
    int hh = (blk >> 5) & 31;
    int b  = blk >> 10;

    __shared__ float sH[64 * 132];
    __shared__ float sCt[64 * 132];
    __shared__ float sP[64];

    int tid = threadIdx.x;
    long hbase = ((long)(b * NH + hh) * NC + c) * (HD * DS);
    long rowbase = (long)b * L_SEQ + c * QCH;

    #pragma unroll
    for (int j = 0; j < 8; j++) {
        int off = j * 1024 + tid * 4;
        int p = off >> 7, n = off & 127;
        *(float4*)&sH[p * 132 + n] = *(const float4*)&Sloc[hbase + off];
    }
    #pragma unroll
    for (int j = 0; j < 8; j++) {
        int off = j * 1024 + tid * 4;
        int t = off >> 7, n = off & 127;
        *(float4*)&sCt[t * 132 + n] = *(const float4*)&proj[(rowbase + t) * PS + 4224 + n];
    }
    if (tid < 64) sP[tid] = expf(clog[(rowbase + tid) * NH + hh]);
    __syncthreads();

    int tx = tid & 15, ty = tid >> 4;
    int pB = tx * 4, tB = ty * 4;
    float acc[4][4] = {};

    for (int n = 0; n < 128; n += 4) {
        float4 cv[4], hv[4];
        #pragma unroll
        for (int i = 0; i < 4; i++) cv[i] = *(const float4*)&sCt[(tB + i) * 132 + n];
        #pragma unroll
        for (int j = 0; j < 4; j++) hv[j] = *(const float4*)&sH[(pB + j) * 132 + n];
        #pragma unroll
        for (int i = 0; i < 4; i++)
            #pragma unroll
            for (int j = 0; j < 4; j++) {
                acc[i][j] = fmaf(cv[i].x, hv[j].x, acc[i][j]);
                acc[i][j] = fmaf(cv[i].y, hv[j].y, acc[i][j]);
                acc[i][j] = fmaf(cv[i].z, hv[j].z, acc[i][j]);
                acc[i][j] = fmaf(cv[i].w, hv[j].w, acc[i][j]);
            }
    }

    #pragma unroll
    for (int i = 0; i < 4; i++) {
        long yoff = (rowbase + tB + i) * DI + hh * HD + pB;
        float pm = sP[tB + i];
        float4 yv = *(const float4*)&yssm[yoff];
        yv.x += pm * acc[i][0];
        yv.y += pm * acc[i][1];
        yv.z += pm * acc[i][2];
        yv.w += pm * acc[i][3];
        *(float4*)&yssm[yoff] = yv;
    }
}

// ---------------------------------------------------------------------------
// Gating: y = (y_ssm + D[h]*x_conv) * silu(z), bf16 out
// ---------------------------------------------------------------------------
__global__ __launch_bounds__(256) void k_gate(const float* __restrict__ proj,
                                              const float* __restrict__ xconv,
                                              const float* __restrict__ Dv,
                                              const float* __restrict__ y,
                                              __bf16* __restrict__ yg) {
    int idx = blockIdx.x * 256 + threadIdx.x;
    int c = idx & (DI - 1);
    int row = idx >> 11;
    int hh = c >> 6;
    float yv = y[idx] + Dv[hh] * xconv[idx];
    float z = proj[(long)row * PS + c];
    yg[idx] = (__bf16)(yv * (z / (1.0f + expf(-z))));
}

// ---------------------------------------------------------------------------
extern "C" void kernel_launch(void* const* d_in, const int* in_sizes, int n_in,
                              void* d_out, int out_size, void* d_ws, size_t ws_size,
                              hipStream_t stream) {
    const float* x       = (const float*)d_in[0];
    const float* norm_w  = (const float*)d_in[1];
    const float* Wp      = (const float*)d_in[2];   // (4384, 1024)
    const float* cw      = (const float*)d_in[3];
    const float* cb      = (const float*)d_in[4];
    const float* A_log   = (const float*)d_in[5];
    const float* Dv      = (const float*)d_in[6];
    const float* dt_bias = (const float*)d_in[7];
    const float* Wo      = (const float*)d_in[8];   // (1024, 2048)
    float* out = (float*)d_out;

    float* ws    = (float*)d_ws;
    float* proj  = ws;                        // 4096*4480 = 18,350,080
    float* xconv = proj  + 18350080;          //  8,388,608
    float* clog  = xconv +  8388608;          //    131,072
    float* yb    = clog  +   131072;          //  8,388,608
    float* U     = yb    +  8388608;          // 16,777,216
    // total 52,035,584 floats = 208 MB

    __bf16* xnb  = (__bf16*)U;
    __bf16* Wpb  = (__bf16*)(U + 2097152);
    float*  Sloc = U;
    __bf16* Wob  = (__bf16*)U;                // 1,048,576 floats of space
    __bf16* ybb  = (__bf16*)(U + 1048576);

    // phase 1: input prep + in_proj GEMM
    k_f2b<<<4384, 256, 0, stream>>>(Wp, Wpb, (DP * DM) / 4);
    k_rmsnorm<<<M_ROWS, 256, 0, stream>>>(x, norm_w, xnb);
    {
        dim3 g(PS / 128, M_ROWS / 128);
        k_gemm_bf<<<g, 256, 0, stream>>>(xnb, Wpb, nullptr, proj, DP, DM, PS);
    }

    k_conv<<<(M_ROWS * DI) / 256, 256, 0, stream>>>(proj, cw, cb, xconv);

    // phase 2: chunked scan via MFMA (Sloc overwrites xnb/Wpb — dead)
    k_chunk<<<B_SZ * NH * NC, 256, 0, stream>>>(proj, xconv, A_log, dt_bias,
                                                clog, yb, Sloc);
    k_carry<<<(B_SZ * NH * HD * DS) / 256, 256, 0, stream>>>(Sloc, clog);
    k_fix<<<B_SZ * NH * NC, 256, 0, stream>>>(proj, Sloc, clog, yb);

    // phase 3: gate + out_proj (Wob/ybb overwrite Sloc — dead)
    k_f2b<<<2048, 256, 0, stream>>>(Wo, Wob, (DM * DI) / 4);
    k_gate<<<(M_ROWS * DI) / 256, 256, 0, stream>>>(proj, xconv, Dv, yb, ybb);
    {
        dim3 g(DM / 128, M_ROWS / 128);
        k_gemm_bf<<<g, 256, 0, stream>>>(ybb, Wob, x, out, DM, DI, DM);
    }
}

// Round 9
// 359.684 us; speedup vs baseline: 4.2083x; 1.1092x over previous
//
#include <hip/hip_runtime.h>
#include <math.h>

#define B_SZ     2
#define L_SEQ    2048
#define DM       1024      // D_MODEL
#define DP       4384      // D_PROJ (logical)
#define PS       4480      // proj padded stride (35 * 128)
#define DI       2048      // D_INNER
#define NH       32        // N_HEADS
#define HD       64        // HEAD_DIM
#define DS       128       // D_STATE
#define M_ROWS   (B_SZ * L_SEQ)   // 4096
#define QCH      64        // scan chunk length
#define NC       (L_SEQ / QCH)    // 32 chunks

typedef __bf16 bf16x8 __attribute__((ext_vector_type(8)));
typedef __bf16 bf16x4 __attribute__((ext_vector_type(4)));
typedef float  f32x4  __attribute__((ext_vector_type(4)));

// ---------------------------------------------------------------------------
// fp32 -> bf16 conversion (weights)
// ---------------------------------------------------------------------------
__global__ __launch_bounds__(256) void k_f2b(const float* __restrict__ src,
                                             __bf16* __restrict__ dst, int n4) {
    int i = blockIdx.x * 256 + threadIdx.x;
    if (i < n4) {
        float4 v = ((const float4*)src)[i];
        bf16x4 o = { (__bf16)v.x, (__bf16)v.y, (__bf16)v.z, (__bf16)v.w };
        ((bf16x4*)dst)[i] = o;
    }
}

// ---------------------------------------------------------------------------
// RMSNorm: one block per row of 1024, float4 in, bf16 out
// ---------------------------------------------------------------------------
__global__ __launch_bounds__(256) void k_rmsnorm(const float* __restrict__ x,
                                                 const float* __restrict__ w,
                                                 __bf16* __restrict__ xn) {
    int row = blockIdx.x;
    int tid = threadIdx.x;
    const float4* x4 = (const float4*)(x + (long)row * DM);
    float4 v = x4[tid];
    float ss = v.x * v.x + v.y * v.y + v.z * v.z + v.w * v.w;
    #pragma unroll
    for (int off = 32; off > 0; off >>= 1) ss += __shfl_xor(ss, off, 64);
    __shared__ float sred[4];
    if ((tid & 63) == 0) sred[tid >> 6] = ss;
    __syncthreads();
    float tot = sred[0] + sred[1] + sred[2] + sred[3];
    float scale = rsqrtf(tot * (1.0f / (float)DM) + 1e-6f);
    const float4* w4 = (const float4*)w;
    float4 wv = w4[tid];
    bf16x4 o = { (__bf16)(v.x * scale * wv.x), (__bf16)(v.y * scale * wv.y),
                 (__bf16)(v.z * scale * wv.z), (__bf16)(v.w * scale * wv.w) };
    ((bf16x4*)(xn + (long)row * DM))[tid] = o;
}

// ---------------------------------------------------------------------------
// bf16 MFMA GEMM (register-staged, R6-verified 78us): C = A @ W^T (+resid).
// 128x128 tile, BK=32, 4 waves, 4x4 mfma_f32_16x16x32_bf16.
// ---------------------------------------------------------------------------
__global__ __launch_bounds__(256) void k_gemm_bf(const __bf16* __restrict__ A,
                                                 const __bf16* __restrict__ W,
                                                 const float* __restrict__ resid,
                                                 float* __restrict__ C,
                                                 int Nw, int K, int ldc) {
    __shared__ __align__(16) __bf16 As[128 * 40];
    __shared__ __align__(16) __bf16 Bs[128 * 40];
    int t = threadIdx.x;
    int bm = blockIdx.y * 128, bn = blockIdx.x * 128;

    int r0 = t >> 2;
    int c0 = (t & 3) * 8;
    int r1 = r0 + 64;
    const __bf16* Ag0 = A + (long)(bm + r0) * K + c0;
    const __bf16* Ag1 = A + (long)(bm + r1) * K + c0;
    int br0 = bn + r0; if (br0 >= Nw) br0 = Nw - 1;
    int br1 = bn + r1; if (br1 >= Nw) br1 = Nw - 1;
    const __bf16* Wg0 = W + (long)br0 * K + c0;
    const __bf16* Wg1 = W + (long)br1 * K + c0;
    __bf16* Al0 = As + r0 * 40 + c0;
    __bf16* Al1 = As + r1 * 40 + c0;
    __bf16* Bl0 = Bs + r0 * 40 + c0;
    __bf16* Bl1 = Bs + r1 * 40 + c0;

    int lane = t & 63, w = t >> 6;
    int wm = (w & 1) * 64, wn = (w >> 1) * 64;
    int ln = lane & 15;
    int kc = (lane >> 4) * 8;
    const __bf16* Ar = As + (wm + ln) * 40 + kc;
    const __bf16* Br = Bs + (wn + ln) * 40 + kc;

    f32x4 acc[4][4] = {};

    for (int k0 = 0; k0 < K; k0 += 32) {
        bf16x8 a0 = *(const bf16x8*)(Ag0 + k0);
        bf16x8 a1 = *(const bf16x8*)(Ag1 + k0);
        bf16x8 b0 = *(const bf16x8*)(Wg0 + k0);
        bf16x8 b1 = *(const bf16x8*)(Wg1 + k0);
        __syncthreads();
        *(bf16x8*)Al0 = a0;
        *(bf16x8*)Al1 = a1;
        *(bf16x8*)Bl0 = b0;
        *(bf16x8*)Bl1 = b1;
        __syncthreads();

        bf16x8 af[4], bfr[4];
        #pragma unroll
        for (int i = 0; i < 4; i++) af[i]  = *(const bf16x8*)(Ar + i * 16 * 40);
        #pragma unroll
        for (int j = 0; j < 4; j++) bfr[j] = *(const bf16x8*)(Br + j * 16 * 40);
        #pragma unroll
        for (int i = 0; i < 4; i++)
            #pragma unroll
            for (int j = 0; j < 4; j++)
                acc[i][j] = __builtin_amdgcn_mfma_f32_16x16x32_bf16(
                                af[i], bfr[j], acc[i][j], 0, 0, 0);
    }

    #pragma unroll
    for (int i = 0; i < 4; i++) {
        #pragma unroll
        for (int r = 0; r < 4; r++) {
            int m = bm + wm + i * 16 + (lane >> 4) * 4 + r;
            long off = (long)m * ldc + bn + wn + ln;
            #pragma unroll
            for (int j = 0; j < 4; j++) {
                float v = acc[i][j][r];
                if (resid != nullptr) v += resid[off + j * 16];
                C[off + j * 16] = v;
            }
        }
    }
}

// ---------------------------------------------------------------------------
// Phase A (MFMA) with fused conv+SiLU+dt/cumlog+D-term (R8 logic, audited):
//   x-halo staged (67 rows), conv K=4 + SiLU in LDS
//   dt = softplus; clog = inclusive scan (wave 0); written to global
//   G=C@B^T; M=causal-decay*G; Y=M@DTX + D[h]*xc; S_loc=sum_s w_s*dtx*B
// ---------------------------------------------------------------------------
__global__ __launch_bounds__(256) void k_chunk(const float* __restrict__ proj,
                                               const float* __restrict__ cw,
                                               const float* __restrict__ cb,
                                               const float* __restrict__ A_log,
                                               const float* __restrict__ dt_bias,
                                               const float* __restrict__ Dv,
                                               float* __restrict__ clog,
                                               float* __restrict__ yssm,
                                               float* __restrict__ Sloc) {
    int blk = blockIdx.x;
    int c  = blk & 31;
    int hh = (blk >> 5) & 31;
    int b  = blk >> 10;
    int tid = threadIdx.x;
    long rowbase = (long)b * L_SEQ + c * QCH;

    __shared__ __align__(16) __bf16 sB[64 * 136];    // B_chunk [s][n]
    __shared__ __align__(16) __bf16 sU[128 * 72];    // ph1: C [t][n] str136; ph2: B^T [n][s] str72
    __shared__ __align__(16) __bf16 sXT[64 * 72];    // dtx^T [p][s]
    __shared__ __align__(16) __bf16 sXCM[67 * 72];   // ph1: raw x [ss][p]; ph2 overlay: M [t][s]
    __shared__ __align__(16) __bf16 sXCo[64 * 72];   // conv-silu output xc [t][p]
    __shared__ float sCW[256];
    __shared__ float sCB[64];
    __shared__ float sclog[64];
    __shared__ float sdt[64];
    __shared__ float sw[64];

    // ---- stage B, C (fp32->bf16) ----
    #pragma unroll
    for (int j = 0; j < 8; j++) {
        int off = j * 256 + tid;
        int t  = off >> 5;
        int n4 = (off & 31) * 4;
        const float* pr = proj + (rowbase + t) * PS;
        float4 bv = *(const float4*)(pr + 4096 + n4);
        float4 cv = *(const float4*)(pr + 4224 + n4);
        bf16x4 bb = {(__bf16)bv.x, (__bf16)bv.y, (__bf16)bv.z, (__bf16)bv.w};
        bf16x4 cc = {(__bf16)cv.x, (__bf16)cv.y, (__bf16)cv.z, (__bf16)cv.w};
        *(bf16x4*)&sB[t * 136 + n4] = bb;
        *(bf16x4*)&sU[t * 136 + n4] = cc;
    }
    // ---- stage raw x rows ss=0..66 (t = ss-3; zero before seq start) ----
    #pragma unroll
    for (int j = 0; j < 5; j++) {
        int off = j * 256 + tid;
        if (off < 1072) {
            int ss = off >> 4;
            int p4 = (off & 15) * 4;
            float4 xv = {0.0f, 0.0f, 0.0f, 0.0f};
            if (c > 0 || ss >= 3)
                xv = *(const float4*)(proj + (rowbase + ss - 3) * PS + DI + hh * HD + p4);
            bf16x4 xb = {(__bf16)xv.x, (__bf16)xv.y, (__bf16)xv.z, (__bf16)xv.w};
            *(bf16x4*)&sXCM[ss * 72 + p4] = xb;
        }
    }
    sCW[tid] = cw[hh * 256 + tid];
    if (tid < 64) sCB[tid] = cb[hh * 64 + tid];

    // ---- wave 0: dt = softplus, clog = inclusive scan, write global ----
    if (tid < 64) {
        float xr = proj[(rowbase + tid) * PS + 4352 + hh] + dt_bias[hh];
        float dt = (xr > 20.0f) ? xr : log1pf(expf(xr));
        float la = -expf(A_log[hh]);
        float v = la * dt;
        #pragma unroll
        for (int off = 1; off < 64; off <<= 1) {
            float u = __shfl_up(v, off, 64);
            if (tid >= off) v += u;
        }
        sdt[tid] = dt;
        sclog[tid] = v;
        clog[(rowbase + tid) * NH + hh] = v;
    }
    __syncthreads();

    // ---- conv K=4 + SiLU: write sXCo [t][p] and sXT [p][t] (dt-scaled) ----
    #pragma unroll
    for (int i = 0; i < 16; i++) {
        int idx = i * 256 + tid;
        int s = idx >> 6;
        int p = idx & 63;
        float acc = sCB[p];
        #pragma unroll
        for (int j = 0; j < 4; j++)
            acc = fmaf(sCW[p * 4 + j], (float)sXCM[(s + j) * 72 + p], acc);
        float xc = acc / (1.0f + expf(-acc));
        sXCo[s * 72 + p] = (__bf16)xc;
        sXT[p * 72 + s] = (__bf16)(sdt[s] * xc);
    }
    if (tid < 64) sw[tid] = expf(sclog[63] - sclog[tid]);
    __syncthreads();   // conv reads of sXCM done -> sXCM reusable as sM

    int lane = tid & 63, w = tid >> 6;
    int ln = lane & 15;
    int quad = lane >> 4;
    int kc = quad * 8;

    // ---- G = C @ B^T ----
    bf16x8 caf[4];
    #pragma unroll
    for (int k0 = 0; k0 < 4; k0++)
        caf[k0] = *(const bf16x8*)&sU[(16 * w + ln) * 136 + kc + k0 * 32];
    f32x4 g[4] = {};
    #pragma unroll
    for (int j = 0; j < 4; j++)
        #pragma unroll
        for (int k0 = 0; k0 < 4; k0++) {
            bf16x8 bf_ = *(const bf16x8*)&sB[(16 * j + ln) * 136 + kc + k0 * 32];
            g[j] = __builtin_amdgcn_mfma_f32_16x16x32_bf16(caf[k0], bf_, g[j], 0, 0, 0);
        }

    // ---- M[t,s] = (s<=t) ? exp(clog_t - clog_s) * G : 0 -> sXCM overlay ----
    {
        int trow = 16 * w + quad * 4;
        #pragma unroll
        for (int r = 0; r < 4; r++) {
            int t = trow + r;
            float ct = sclog[t];
            #pragma unroll
            for (int j = 0; j < 4; j++) {
                int s = 16 * j + ln;
                float v = (s <= t) ? g[j][r] * expf(ct - sclog[s]) : 0.0f;
                sXCM[t * 72 + s] = (__bf16)v;
            }
        }
    }
    __syncthreads();   // sM complete; sU (C) now dead

    // ---- transpose sB -> sU as B^T [n][s] (stride 72) ----
    #pragma unroll
    for (int j = 0; j < 4; j++) {
        int s  = tid & 63;
        int n8 = (j * 4 + (tid >> 6)) * 8;
        bf16x8 v = *(const bf16x8*)&sB[s * 136 + n8];
        #pragma unroll
        for (int k = 0; k < 8; k++) sU[(n8 + k) * 72 + s] = v[k];
    }

    // ---- Y = M @ DTX + D[h]*xc ----
    {
        float Dh = Dv[hh];
        bf16x8 maf[2];
        #pragma unroll
        for (int k0 = 0; k0 < 2; k0++)
            maf[k0] = *(const bf16x8*)&sXCM[(16 * w + ln) * 72 + kc + k0 * 32];
        f32x4 y[4] = {};
        #pragma unroll
        for (int j = 0; j < 4; j++)
            #pragma unroll
            for (int k0 = 0; k0 < 2; k0++) {
                bf16x8 xf = *(const bf16x8*)&sXT[(16 * j + ln) * 72 + kc + k0 * 32];
                y[j] = __builtin_amdgcn_mfma_f32_16x16x32_bf16(maf[k0], xf, y[j], 0, 0, 0);
            }
        #pragma unroll
        for (int j = 0; j < 4; j++)
            #pragma unroll
            for (int r = 0; r < 4; r++) {
                int t = 16 * w + quad * 4 + r;
                int p = 16 * j + ln;
                float v = y[j][r] + Dh * (float)sXCo[t * 72 + p];
                yssm[(rowbase + t) * DI + hh * HD + p] = v;
            }
    }
    __syncthreads();   // sU (B^T) complete

    // ---- S_loc[p,n] = sum_s w_s * dtx[s,p] * B[s,n] ----
    {
        bf16x8 xaf[2];
        #pragma unroll
        for (int k0 = 0; k0 < 2; k0++) {
            bf16x8 raw = *(const bf16x8*)&sXT[(16 * w + ln) * 72 + kc + k0 * 32];
            bf16x8 sc;
            #pragma unroll
            for (int jj = 0; jj < 8; jj++) {
                int s = kc + k0 * 32 + jj;
                sc[jj] = (__bf16)((float)raw[jj] * sw[s]);
            }
            xaf[k0] = sc;
        }
        f32x4 sacc[8] = {};
        #pragma unroll
        for (int j = 0; j < 8; j++)
            #pragma unroll
            for (int k0 = 0; k0 < 2; k0++) {
                bf16x8 btf = *(const bf16x8*)&sU[(16 * j + ln) * 72 + kc + k0 * 32];
                sacc[j] = __builtin_amdgcn_mfma_f32_16x16x32_bf16(xaf[k0], btf, sacc[j], 0, 0, 0);
            }
        long sbase = ((long)(b * NH + hh) * NC + c) * (HD * DS);
        #pragma unroll
        for (int j = 0; j < 8; j++)
            #pragma unroll
            for (int r = 0; r < 4; r++) {
                int p = 16 * w + quad * 4 + r;
                int n = 16 * j + ln;
                Sloc[sbase + p * DS + n] = sacc[j][r];
            }
    }
}

// ---------------------------------------------------------------------------
// Phase B: sequential carry over chunks (in-place: S_c -> H_in(c))
// ---------------------------------------------------------------------------
__global__ __launch_bounds__(256) void k_carry(float* __restrict__ Sloc,
                                               const float* __restrict__ clog) {
    int idx = blockIdx.x * 256 + threadIdx.x;   // < 524288
    int n  = idx & 127;
    int p  = (idx >> 7) & 63;
    int hh = (idx >> 13) & 31;
    int b  = idx >> 18;
    long base = ((long)(b * NH + hh) * NC) * (HD * DS) + p * DS + n;
    float T = 0.0f;
    for (int c = 0; c < NC; c++) {
        float lam = expf(clog[((long)b * L_SEQ + c * QCH + QCH - 1) * NH + hh]);
        long a = base + (long)c * (HD * DS);
        float S = Sloc[a];
        Sloc[a] = T;
        T = fmaf(T, lam, S);
    }
}

// ---------------------------------------------------------------------------
// Phase C + gate: yg = (yb + exp(clog_t)*(C_t . Hin[p,:])) * silu(z), bf16
// ---------------------------------------------------------------------------
__global__ __launch_bounds__(256, 2) void k_fix(const float* __restrict__ proj,
                                                const float* __restrict__ Sloc,
                                                const float* __restrict__ clog,
                                                const float* __restrict__ yb,
                                                __bf16* __restrict__ yg) {
    int blk = blockIdx.x;
    int c  = blk & 31;
    int hh = (blk >> 5) & 31;
    int b  = blk >> 10;

    __shared__ float sH[64 * 132];
    __shared__ float sCt[64 * 132];
    __shared__ float sP[64];

    int tid = threadIdx.x;
    long hbase = ((long)(b * NH + hh) * NC + c) * (HD * DS);
    long rowbase = (long)b * L_SEQ + c * QCH;

    #pragma unroll
    for (int j = 0; j < 8; j++) {
        int off = j * 1024 + tid * 4;
        int p = off >> 7, n = off & 127;
        *(float4*)&sH[p * 132 + n] = *(const float4*)&Sloc[hbase + off];
    }
    #pragma unroll
    for (int j = 0; j < 8; j++) {
        int off = j * 1024 + tid * 4;
        int t = off >> 7, n = off & 127;
        *(float4*)&sCt[t * 132 + n] = *(const float4*)&proj[(rowbase + t) * PS + 4224 + n];
    }
    if (tid < 64) sP[tid] = expf(clog[(rowbase + tid) * NH + hh]);
    __syncthreads();

    int tx = tid & 15, ty = tid >> 4;
    int pB = tx * 4, tB = ty * 4;
    float acc[4][4] = {};

    for (int n = 0; n < 128; n += 4) {
        float4 cv[4], hv[4];
        #pragma unroll
        for (int i = 0; i < 4; i++) cv[i] = *(const float4*)&sCt[(tB + i) * 132 + n];
        #pragma unroll
        for (int j = 0; j < 4; j++) hv[j] = *(const float4*)&sH[(pB + j) * 132 + n];
        #pragma unroll
        for (int i = 0; i < 4; i++)
            #pragma unroll
            for (int j = 0; j < 4; j++) {
                acc[i][j] = fmaf(cv[i].x, hv[j].x, acc[i][j]);
                acc[i][j] = fmaf(cv[i].y, hv[j].y, acc[i][j]);
                acc[i][j] = fmaf(cv[i].z, hv[j].z, acc[i][j]);
                acc[i][j] = fmaf(cv[i].w, hv[j].w, acc[i][j]);
            }
    }

    #pragma unroll
    for (int i = 0; i < 4; i++) {
        long row = rowbase + tB + i;
        long yoff = row * DI + hh * HD + pB;
        float pm = sP[tB + i];
        float4 yv = *(const float4*)&yb[yoff];
        float4 zv = *(const float4*)&proj[row * PS + hh * HD + pB];
        float o0 = (yv.x + pm * acc[i][0]) * (zv.x / (1.0f + expf(-zv.x)));
        float o1 = (yv.y + pm * acc[i][1]) * (zv.y / (1.0f + expf(-zv.y)));
        float o2 = (yv.z + pm * acc[i][2]) * (zv.z / (1.0f + expf(-zv.z)));
        float o3 = (yv.w + pm * acc[i][3]) * (zv.w / (1.0f + expf(-zv.w)));
        bf16x4 ob = {(__bf16)o0, (__bf16)o1, (__bf16)o2, (__bf16)o3};
        *(bf16x4*)&yg[yoff] = ob;
    }
}

// ---------------------------------------------------------------------------
extern "C" void kernel_launch(void* const* d_in, const int* in_sizes, int n_in,
                              void* d_out, int out_size, void* d_ws, size_t ws_size,
                              hipStream_t stream) {
    const float* x       = (const float*)d_in[0];
    const float* norm_w  = (const float*)d_in[1];
    const float* Wp      = (const float*)d_in[2];   // (4384, 1024)
    const float* cw      = (const float*)d_in[3];
    const float* cb      = (const float*)d_in[4];
    const float* A_log   = (const float*)d_in[5];
    const float* Dv      = (const float*)d_in[6];
    const float* dt_bias = (const float*)d_in[7];
    const float* Wo      = (const float*)d_in[8];   // (1024, 2048)
    float* out = (float*)d_out;

    // FIX (R8 bug): ybb needs M_ROWS*DI bf16 = 4,194,304 floats of space.
    // R8 gave it 1,048,576 -> tail overflowed into U (Sloc / Wob) -> absmax 9.1.
    float* ws    = (float*)d_ws;
    float* proj  = ws;                        // 18,350,080
    float* clog  = proj + 18350080;           //    131,072
    float* yb    = clog + 131072;             //  8,388,608
    float* ybf   = yb   + 8388608;            //  4,194,304 (8,388,608 bf16)
    float* U     = ybf  + 4194304;            // 16,777,216
    // total 47,841,280 floats = 191.4 MB

    __bf16* xnb  = (__bf16*)U;
    __bf16* Wpb  = (__bf16*)(U + 2097152);
    float*  Sloc = U;
    __bf16* Wob  = (__bf16*)U;
    __bf16* ybb  = (__bf16*)ybf;              // fully outside U now

    // phase 1: input prep + in_proj GEMM
    k_f2b<<<4384, 256, 0, stream>>>(Wp, Wpb, (DP * DM) / 4);
    k_rmsnorm<<<M_ROWS, 256, 0, stream>>>(x, norm_w, xnb);
    {
        dim3 g(PS / 128, M_ROWS / 128);
        k_gemm_bf<<<g, 256, 0, stream>>>(xnb, Wpb, nullptr, proj, DP, DM, PS);
    }

    // phase 2: chunked scan w/ fused conv+dt (Sloc overwrites xnb/Wpb — dead)
    k_chunk<<<B_SZ * NH * NC, 256, 0, stream>>>(proj, cw, cb, A_log, dt_bias,
                                                Dv, clog, yb, Sloc);
    k_carry<<<(B_SZ * NH * HD * DS) / 256, 256, 0, stream>>>(Sloc, clog);
    k_fix<<<B_SZ * NH * NC, 256, 0, stream>>>(proj, Sloc, clog, yb, ybb);

    // phase 3: out_proj (Wob overwrites Sloc — dead after k_fix)
    k_f2b<<<2048, 256, 0, stream>>>(Wo, Wob, (DM * DI) / 4);
    {
        dim3 g(DM / 128, M_ROWS / 128);
        k_gemm_bf<<<g, 256, 0, stream>>>(ybb, Wob, x, out, DM, DI, DM);
    }
}

// Round 10
// 322.963 us; speedup vs baseline: 4.6868x; 1.1137x over previous
//
#include <hip/hip_runtime.h>
#include <math.h>

#define B_SZ     2
#define L_SEQ    2048
#define DM       1024      // D_MODEL
#define DP       4384      // D_PROJ (logical)
#define PS       4480      // proj padded stride (35 * 128)
#define DI       2048      // D_INNER
#define NH       32        // N_HEADS
#define HD       64        // HEAD_DIM
#define DS       128       // D_STATE
#define M_ROWS   (B_SZ * L_SEQ)   // 4096
#define QCH      64        // scan chunk length
#define NC       (L_SEQ / QCH)    // 32 chunks

typedef __bf16 bf16x8 __attribute__((ext_vector_type(8)));
typedef __bf16 bf16x4 __attribute__((ext_vector_type(4)));
typedef float  f32x4  __attribute__((ext_vector_type(4)));

// ---------------------------------------------------------------------------
// fp32 -> bf16 conversion (weights)
// ---------------------------------------------------------------------------
__global__ __launch_bounds__(256) void k_f2b(const float* __restrict__ src,
                                             __bf16* __restrict__ dst, int n4) {
    int i = blockIdx.x * 256 + threadIdx.x;
    if (i < n4) {
        float4 v = ((const float4*)src)[i];
        bf16x4 o = { (__bf16)v.x, (__bf16)v.y, (__bf16)v.z, (__bf16)v.w };
        ((bf16x4*)dst)[i] = o;
    }
}

// ---------------------------------------------------------------------------
// RMSNorm: one block per row of 1024, float4 in, bf16 out
// ---------------------------------------------------------------------------
__global__ __launch_bounds__(256) void k_rmsnorm(const float* __restrict__ x,
                                                 const float* __restrict__ w,
                                                 __bf16* __restrict__ xn) {
    int row = blockIdx.x;
    int tid = threadIdx.x;
    const float4* x4 = (const float4*)(x + (long)row * DM);
    float4 v = x4[tid];
    float ss = v.x * v.x + v.y * v.y + v.z * v.z + v.w * v.w;
    #pragma unroll
    for (int off = 32; off > 0; off >>= 1) ss += __shfl_xor(ss, off, 64);
    __shared__ float sred[4];
    if ((tid & 63) == 0) sred[tid >> 6] = ss;
    __syncthreads();
    float tot = sred[0] + sred[1] + sred[2] + sred[3];
    float scale = rsqrtf(tot * (1.0f / (float)DM) + 1e-6f);
    const float4* w4 = (const float4*)w;
    float4 wv = w4[tid];
    bf16x4 o = { (__bf16)(v.x * scale * wv.x), (__bf16)(v.y * scale * wv.y),
                 (__bf16)(v.z * scale * wv.z), (__bf16)(v.w * scale * wv.w) };
    ((bf16x4*)(xn + (long)row * DM))[tid] = o;
}

// ---------------------------------------------------------------------------
// bf16 MFMA GEMM (register-staged, R6/R9-verified): 128x128 tile, BK=32.
// Output: if Cb != null -> bf16 store (no resid), plus fp32 side-store of
// logical cols [4352,4384) into Dt (dt_raw kept fp32: its rounding compounds
// through the 64-step cumlog exponent). Else fp32 store (+resid).
// ---------------------------------------------------------------------------
__global__ __launch_bounds__(256) void k_gemm_bf(const __bf16* __restrict__ A,
                                                 const __bf16* __restrict__ W,
                                                 const float* __restrict__ resid,
                                                 float* __restrict__ Cf,
                                                 __bf16* __restrict__ Cb,
                                                 float* __restrict__ Dt,
                                                 int Nw, int K, int ldc) {
    __shared__ __align__(16) __bf16 As[128 * 40];
    __shared__ __align__(16) __bf16 Bs[128 * 40];
    int t = threadIdx.x;
    int bm = blockIdx.y * 128, bn = blockIdx.x * 128;

    int r0 = t >> 2;
    int c0 = (t & 3) * 8;
    int r1 = r0 + 64;
    const __bf16* Ag0 = A + (long)(bm + r0) * K + c0;
    const __bf16* Ag1 = A + (long)(bm + r1) * K + c0;
    int br0 = bn + r0; if (br0 >= Nw) br0 = Nw - 1;
    int br1 = bn + r1; if (br1 >= Nw) br1 = Nw - 1;
    const __bf16* Wg0 = W + (long)br0 * K + c0;
    const __bf16* Wg1 = W + (long)br1 * K + c0;
    __bf16* Al0 = As + r0 * 40 + c0;
    __bf16* Al1 = As + r1 * 40 + c0;
    __bf16* Bl0 = Bs + r0 * 40 + c0;
    __bf16* Bl1 = Bs + r1 * 40 + c0;

    int lane = t & 63, w = t >> 6;
    int wm = (w & 1) * 64, wn = (w >> 1) * 64;
    int ln = lane & 15;
    int kc = (lane >> 4) * 8;
    const __bf16* Ar = As + (wm + ln) * 40 + kc;
    const __bf16* Br = Bs + (wn + ln) * 40 + kc;

    f32x4 acc[4][4] = {};

    for (int k0 = 0; k0 < K; k0 += 32) {
        bf16x8 a0 = *(const bf16x8*)(Ag0 + k0);
        bf16x8 a1 = *(const bf16x8*)(Ag1 + k0);
        bf16x8 b0 = *(const bf16x8*)(Wg0 + k0);
        bf16x8 b1 = *(const bf16x8*)(Wg1 + k0);
        __syncthreads();
        *(bf16x8*)Al0 = a0;
        *(bf16x8*)Al1 = a1;
        *(bf16x8*)Bl0 = b0;
        *(bf16x8*)Bl1 = b1;
        __syncthreads();

        bf16x8 af[4], bfr[4];
        #pragma unroll
        for (int i = 0; i < 4; i++) af[i]  = *(const bf16x8*)(Ar + i * 16 * 40);
        #pragma unroll
        for (int j = 0; j < 4; j++) bfr[j] = *(const bf16x8*)(Br + j * 16 * 40);
        #pragma unroll
        for (int i = 0; i < 4; i++)
            #pragma unroll
            for (int j = 0; j < 4; j++)
                acc[i][j] = __builtin_amdgcn_mfma_f32_16x16x32_bf16(
                                af[i], bfr[j], acc[i][j], 0, 0, 0);
    }

    int colbase = bn + wn + ln;
    #pragma unroll
    for (int i = 0; i < 4; i++) {
        #pragma unroll
        for (int r = 0; r < 4; r++) {
            int m = bm + wm + i * 16 + (lane >> 4) * 4 + r;
            long off = (long)m * ldc + colbase;
            #pragma unroll
            for (int j = 0; j < 4; j++) {
                float v = acc[i][j][r];
                if (Cb != nullptr) {
                    Cb[off + j * 16] = (__bf16)v;
                    if (Dt != nullptr) {
                        int col = colbase + j * 16;
                        if (col >= 4352 && col < 4384)
                            Dt[(long)m * 32 + (col - 4352)] = v;
                    }
                } else {
                    if (resid != nullptr) v += resid[off + j * 16];
                    Cf[off + j * 16] = v;
                }
            }
        }
    }
}

// ---------------------------------------------------------------------------
// Phase A (MFMA) fused conv+SiLU+dt/cumlog+D-term; proj now bf16, dt_raw
// read from the fp32 side-buffer.
// ---------------------------------------------------------------------------
__global__ __launch_bounds__(256) void k_chunk(const __bf16* __restrict__ projb,
                                               const float* __restrict__ dtraw,
                                               const float* __restrict__ cw,
                                               const float* __restrict__ cb,
                                               const float* __restrict__ A_log,
                                               const float* __restrict__ dt_bias,
                                               const float* __restrict__ Dv,
                                               float* __restrict__ clog,
                                               float* __restrict__ yssm,
                                               float* __restrict__ Sloc) {
    int blk = blockIdx.x;
    int c  = blk & 31;
    int hh = (blk >> 5) & 31;
    int b  = blk >> 10;
    int tid = threadIdx.x;
    long rowbase = (long)b * L_SEQ + c * QCH;

    __shared__ __align__(16) __bf16 sB[64 * 136];    // B_chunk [s][n]
    __shared__ __align__(16) __bf16 sU[128 * 72];    // ph1: C [t][n] str136; ph2: B^T [n][s] str72
    __shared__ __align__(16) __bf16 sXT[64 * 72];    // dtx^T [p][s]
    __shared__ __align__(16) __bf16 sXCM[67 * 72];   // ph1: raw x [ss][p]; ph2 overlay: M [t][s]
    __shared__ __align__(16) __bf16 sXCo[64 * 72];   // conv-silu output xc [t][p]
    __shared__ float sCW[256];
    __shared__ float sCB[64];
    __shared__ float sclog[64];
    __shared__ float sdt[64];
    __shared__ float sw[64];

    // ---- stage B, C (bf16 direct) ----
    #pragma unroll
    for (int j = 0; j < 4; j++) {
        int off = j * 256 + tid;          // 1024 bf16x8 = 64 rows * 16
        int t  = off >> 4;
        int n8 = (off & 15) * 8;
        const __bf16* pr = projb + (rowbase + t) * (long)PS;
        *(bf16x8*)&sB[t * 136 + n8] = *(const bf16x8*)(pr + 4096 + n8);
        *(bf16x8*)&sU[t * 136 + n8] = *(const bf16x8*)(pr + 4224 + n8);
    }
    // ---- stage raw x rows ss=0..66 (t = ss-3; zero before seq start) ----
    #pragma unroll
    for (int j = 0; j < 3; j++) {
        int off = j * 256 + tid;          // need 536 = 67 rows * 8 chunks
        if (off < 536) {
            int ss = off >> 3;
            int p8 = (off & 7) * 8;
            bf16x8 xv;
            #pragma unroll
            for (int k = 0; k < 8; k++) xv[k] = (__bf16)0.0f;
            if (c > 0 || ss >= 3)
                xv = *(const bf16x8*)(projb + (rowbase + ss - 3) * (long)PS + DI + hh * HD + p8);
            *(bf16x8*)&sXCM[ss * 72 + p8] = xv;
        }
    }
    sCW[tid] = cw[hh * 256 + tid];
    if (tid < 64) sCB[tid] = cb[hh * 64 + tid];

    // ---- wave 0: dt = softplus (fp32 dtraw), clog = inclusive scan ----
    if (tid < 64) {
        float xr = dtraw[(rowbase + tid) * 32 + hh] + dt_bias[hh];
        float dt = (xr > 20.0f) ? xr : log1pf(expf(xr));
        float la = -expf(A_log[hh]);
        float v = la * dt;
        #pragma unroll
        for (int off = 1; off < 64; off <<= 1) {
            float u = __shfl_up(v, off, 64);
            if (tid >= off) v += u;
        }
        sdt[tid] = dt;
        sclog[tid] = v;
        clog[(rowbase + tid) * NH + hh] = v;
    }
    __syncthreads();

    // ---- conv K=4 + SiLU: write sXCo [t][p] and sXT [p][t] (dt-scaled) ----
    #pragma unroll
    for (int i = 0; i < 16; i++) {
        int idx = i * 256 + tid;
        int s = idx >> 6;
        int p = idx & 63;
        float acc = sCB[p];
        #pragma unroll
        for (int j = 0; j < 4; j++)
            acc = fmaf(sCW[p * 4 + j], (float)sXCM[(s + j) * 72 + p], acc);
        float xc = acc / (1.0f + expf(-acc));
        sXCo[s * 72 + p] = (__bf16)xc;
        sXT[p * 72 + s] = (__bf16)(sdt[s] * xc);
    }
    if (tid < 64) sw[tid] = expf(sclog[63] - sclog[tid]);
    __syncthreads();   // conv reads of sXCM done -> sXCM reusable as sM

    int lane = tid & 63, w = tid >> 6;
    int ln = lane & 15;
    int quad = lane >> 4;
    int kc = quad * 8;

    // ---- G = C @ B^T ----
    bf16x8 caf[4];
    #pragma unroll
    for (int k0 = 0; k0 < 4; k0++)
        caf[k0] = *(const bf16x8*)&sU[(16 * w + ln) * 136 + kc + k0 * 32];
    f32x4 g[4] = {};
    #pragma unroll
    for (int j = 0; j < 4; j++)
        #pragma unroll
        for (int k0 = 0; k0 < 4; k0++) {
            bf16x8 bf_ = *(const bf16x8*)&sB[(16 * j + ln) * 136 + kc + k0 * 32];
            g[j] = __builtin_amdgcn_mfma_f32_16x16x32_bf16(caf[k0], bf_, g[j], 0, 0, 0);
        }

    // ---- M[t,s] = (s<=t) ? exp(clog_t - clog_s) * G : 0 -> sXCM overlay ----
    {
        int trow = 16 * w + quad * 4;
        #pragma unroll
        for (int r = 0; r < 4; r++) {
            int t = trow + r;
            float ct = sclog[t];
            #pragma unroll
            for (int j = 0; j < 4; j++) {
                int s = 16 * j + ln;
                float v = (s <= t) ? g[j][r] * expf(ct - sclog[s]) : 0.0f;
                sXCM[t * 72 + s] = (__bf16)v;
            }
        }
    }
    __syncthreads();   // sM complete; sU (C) now dead

    // ---- transpose sB -> sU as B^T [n][s] (stride 72) ----
    #pragma unroll
    for (int j = 0; j < 4; j++) {
        int s  = tid & 63;
        int n8 = (j * 4 + (tid >> 6)) * 8;
        bf16x8 v = *(const bf16x8*)&sB[s * 136 + n8];
        #pragma unroll
        for (int k = 0; k < 8; k++) sU[(n8 + k) * 72 + s] = v[k];
    }

    // ---- Y = M @ DTX + D[h]*xc ----
    {
        float Dh = Dv[hh];
        bf16x8 maf[2];
        #pragma unroll
        for (int k0 = 0; k0 < 2; k0++)
            maf[k0] = *(const bf16x8*)&sXCM[(16 * w + ln) * 72 + kc + k0 * 32];
        f32x4 y[4] = {};
        #pragma unroll
        for (int j = 0; j < 4; j++)
            #pragma unroll
            for (int k0 = 0; k0 < 2; k0++) {
                bf16x8 xf = *(const bf16x8*)&sXT[(16 * j + ln) * 72 + kc + k0 * 32];
                y[j] = __builtin_amdgcn_mfma_f32_16x16x32_bf16(maf[k0], xf, y[j], 0, 0, 0);
            }
        #pragma unroll
        for (int j = 0; j < 4; j++)
            #pragma unroll
            for (int r = 0; r < 4; r++) {
                int t = 16 * w + quad * 4 + r;
                int p = 16 * j + ln;
                float v = y[j][r] + Dh * (float)sXCo[t * 72 + p];
                yssm[(rowbase + t) * DI + hh * HD + p] = v;
            }
    }
    __syncthreads();   // sU (B^T) complete

    // ---- S_loc[p,n] = sum_s w_s * dtx[s,p] * B[s,n] ----
    {
        bf16x8 xaf[2];
        #pragma unroll
        for (int k0 = 0; k0 < 2; k0++) {
            bf16x8 raw = *(const bf16x8*)&sXT[(16 * w + ln) * 72 + kc + k0 * 32];
            bf16x8 sc;
            #pragma unroll
            for (int jj = 0; jj < 8; jj++) {
                int s = kc + k0 * 32 + jj;
                sc[jj] = (__bf16)((float)raw[jj] * sw[s]);
            }
            xaf[k0] = sc;
        }
        f32x4 sacc[8] = {};
        #pragma unroll
        for (int j = 0; j < 8; j++)
            #pragma unroll
            for (int k0 = 0; k0 < 2; k0++) {
                bf16x8 btf = *(const bf16x8*)&sU[(16 * j + ln) * 72 + kc + k0 * 32];
                sacc[j] = __builtin_amdgcn_mfma_f32_16x16x32_bf16(xaf[k0], btf, sacc[j], 0, 0, 0);
            }
        long sbase = ((long)(b * NH + hh) * NC + c) * (HD * DS);
        #pragma unroll
        for (int j = 0; j < 8; j++)
            #pragma unroll
            for (int r = 0; r < 4; r++) {
                int p = 16 * w + quad * 4 + r;
                int n = 16 * j + ln;
                Sloc[sbase + p * DS + n] = sacc[j][r];
            }
    }
}

// ---------------------------------------------------------------------------
// Phase B: sequential carry over chunks (in-place: S_c -> H_in(c))
// ---------------------------------------------------------------------------
__global__ __launch_bounds__(256) void k_carry(float* __restrict__ Sloc,
                                               const float* __restrict__ clog) {
    int idx = blockIdx.x * 256 + threadIdx.x;   // < 524288
    int n  = idx & 127;
    int p  = (idx >> 7) & 63;
    int hh = (idx >> 13) & 31;
    int b  = idx >> 18;
    long base = ((long)(b * NH + hh) * NC) * (HD * DS) + p * DS + n;
    float T = 0.0f;
    for (int c = 0; c < NC; c++) {
        float lam = expf(clog[((long)b * L_SEQ + c * QCH + QCH - 1) * NH + hh]);
        long a = base + (long)c * (HD * DS);
        float S = Sloc[a];
        Sloc[a] = T;
        T = fmaf(T, lam, S);
    }
}

// ---------------------------------------------------------------------------
// Phase C + gate (MFMA): Ycorr = C_chunk @ Hin^T (64x64, K=128), then
// yg = (yb + exp(clog_t)*Ycorr) * silu(z), bf16 out.
// A-frag = C rows (t), B-frag = H rows (p) -> D[t][p]; layouts as k_gemm_bf.
// ---------------------------------------------------------------------------
__global__ __launch_bounds__(256, 2) void k_fix(const __bf16* __restrict__ projb,
                                                const float* __restrict__ Sloc,
                                                const float* __restrict__ clog,
                                                const float* __restrict__ yb,
                                                __bf16* __restrict__ yg) {
    int blk = blockIdx.x;
    int c  = blk & 31;
    int hh = (blk >> 5) & 31;
    int b  = blk >> 10;

    __shared__ __align__(16) __bf16 sC[64 * 136];   // C [t][n]
    __shared__ __align__(16) __bf16 sH[64 * 136];   // Hin [p][n]
    __shared__ float sP[64];

    int tid = threadIdx.x;
    long hbase = ((long)(b * NH + hh) * NC + c) * (HD * DS);
    long rowbase = (long)b * L_SEQ + c * QCH;

    #pragma unroll
    for (int j = 0; j < 4; j++) {
        int off = j * 256 + tid;          // 1024 bf16x8
        int t  = off >> 4;
        int n8 = (off & 15) * 8;
        *(bf16x8*)&sC[t * 136 + n8] =
            *(const bf16x8*)(projb + (rowbase + t) * (long)PS + 4224 + n8);
    }
    #pragma unroll
    for (int j = 0; j < 8; j++) {
        int off = j * 256 + tid;          // 2048 float4
        int p  = off >> 5;
        int n4 = (off & 31) * 4;
        float4 hv = *(const float4*)&Sloc[hbase + (long)off * 4];
        bf16x4 hb = {(__bf16)hv.x, (__bf16)hv.y, (__bf16)hv.z, (__bf16)hv.w};
        *(bf16x4*)&sH[p * 136 + n4] = hb;
    }
    if (tid < 64) sP[tid] = expf(clog[(rowbase + tid) * NH + hh]);
    __syncthreads();

    int lane = tid & 63, w = tid >> 6;
    int ln = lane & 15;
    int quad = lane >> 4;
    int kc = quad * 8;

    bf16x8 caf[4];
    #pragma unroll
    for (int k0 = 0; k0 < 4; k0++)
        caf[k0] = *(const bf16x8*)&sC[(16 * w + ln) * 136 + kc + k0 * 32];
    f32x4 acc4[4] = {};
    #pragma unroll
    for (int j = 0; j < 4; j++)
        #pragma unroll
        for (int k0 = 0; k0 < 4; k0++) {
            bf16x8 hf = *(const bf16x8*)&sH[(16 * j + ln) * 136 + kc + k0 * 32];
            acc4[j] = __builtin_amdgcn_mfma_f32_16x16x32_bf16(caf[k0], hf, acc4[j], 0, 0, 0);
        }

    #pragma unroll
    for (int j = 0; j < 4; j++)
        #pragma unroll
        for (int r = 0; r < 4; r++) {
            int t = 16 * w + quad * 4 + r;
            int p = 16 * j + ln;
            long row = rowbase + t;
            long yoff = row * DI + hh * HD + p;
            float pm = sP[t];
            float z = (float)projb[row * (long)PS + hh * HD + p];
            float o = (yb[yoff] + pm * acc4[j][r]) * (z / (1.0f + expf(-z)));
            yg[yoff] = (__bf16)o;
        }
}

// ---------------------------------------------------------------------------
extern "C" void kernel_launch(void* const* d_in, const int* in_sizes, int n_in,
                              void* d_out, int out_size, void* d_ws, size_t ws_size,
                              hipStream_t stream) {
    const float* x       = (const float*)d_in[0];
    const float* norm_w  = (const float*)d_in[1];
    const float* Wp      = (const float*)d_in[2];   // (4384, 1024)
    const float* cw      = (const float*)d_in[3];
    const float* cb      = (const float*)d_in[4];
    const float* A_log   = (const float*)d_in[5];
    const float* Dv      = (const float*)d_in[6];
    const float* dt_bias = (const float*)d_in[7];
    const float* Wo      = (const float*)d_in[8];   // (1024, 2048)
    float* out = (float*)d_out;

    // workspace (floats):
    float* ws    = (float*)d_ws;
    __bf16* projb = (__bf16*)ws;              // 18,350,080 bf16 = 9,175,040 fl
    float* dtraw = ws    + 9175040;           //    131,072
    float* clog  = dtraw + 131072;            //    131,072
    float* yb    = clog  + 131072;            //  8,388,608
    float* ybf   = yb    + 8388608;           //  4,194,304 (= 8,388,608 bf16)
    float* U     = ybf   + 4194304;           // 16,777,216
    // total 38,797,312 floats = 155.2 MB

    __bf16* xnb  = (__bf16*)U;
    __bf16* Wpb  = (__bf16*)(U + 2097152);
    float*  Sloc = U;
    __bf16* Wob  = (__bf16*)U;
    __bf16* ybb  = (__bf16*)ybf;

    // phase 1: input prep + in_proj GEMM (bf16 out + fp32 dt side-buffer)
    k_f2b<<<4384, 256, 0, stream>>>(Wp, Wpb, (DP * DM) / 4);
    k_rmsnorm<<<M_ROWS, 256, 0, stream>>>(x, norm_w, xnb);
    {
        dim3 g(PS / 128, M_ROWS / 128);
        k_gemm_bf<<<g, 256, 0, stream>>>(xnb, Wpb, nullptr, nullptr, projb,
                                         dtraw, DP, DM, PS);
    }

    // phase 2: chunked scan (Sloc overwrites xnb/Wpb — dead)
    k_chunk<<<B_SZ * NH * NC, 256, 0, stream>>>(projb, dtraw, cw, cb, A_log,
                                                dt_bias, Dv, clog, yb, Sloc);
    k_carry<<<(B_SZ * NH * HD * DS) / 256, 256, 0, stream>>>(Sloc, clog);
    k_fix<<<B_SZ * NH * NC, 256, 0, stream>>>(projb, Sloc, clog, yb, ybb);

    // phase 3: out_proj (Wob overwrites Sloc — dead after k_fix)
    k_f2b<<<2048, 256, 0, stream>>>(Wo, Wob, (DM * DI) / 4);
    {
        dim3 g(DM / 128, M_ROWS / 128);
        k_gemm_bf<<<g, 256, 0, stream>>>(ybb, Wob, x, out, nullptr, nullptr,
                                         DM, DI, DM);
    }
}

// Round 11
// 306.380 us; speedup vs baseline: 4.9405x; 1.0541x over previous
//
#include <hip/hip_runtime.h>
#include <math.h>

#define B_SZ     2
#define L_SEQ    2048
#define DM       1024      // D_MODEL
#define DP       4384      // D_PROJ (logical)
#define PS       4480      // proj padded stride (35 * 128)
#define DI       2048      // D_INNER
#define NH       32        // N_HEADS
#define HD       64        // HEAD_DIM
#define DS       128       // D_STATE
#define M_ROWS   (B_SZ * L_SEQ)   // 4096
#define QCH      64        // scan chunk length
#define NC       (L_SEQ / QCH)    // 32 chunks

typedef __bf16 bf16x8 __attribute__((ext_vector_type(8)));
typedef __bf16 bf16x4 __attribute__((ext_vector_type(4)));
typedef float  f32x4  __attribute__((ext_vector_type(4)));

// ---------------------------------------------------------------------------
// Fused: f2b(Wp) [blocks 0..4383] + RMSNorm [blocks 4384..8479]
// ---------------------------------------------------------------------------
__global__ __launch_bounds__(256) void k_prep(const float* __restrict__ Wp,
                                              __bf16* __restrict__ Wpb,
                                              const float* __restrict__ x,
                                              const float* __restrict__ w,
                                              __bf16* __restrict__ xn) {
    int tid = threadIdx.x;
    if (blockIdx.x < 4384) {
        int i = blockIdx.x * 256 + tid;          // < (DP*DM)/4
        float4 v = ((const float4*)Wp)[i];
        bf16x4 o = { (__bf16)v.x, (__bf16)v.y, (__bf16)v.z, (__bf16)v.w };
        ((bf16x4*)Wpb)[i] = o;
        return;
    }
    int row = blockIdx.x - 4384;
    const float4* x4 = (const float4*)(x + (long)row * DM);
    float4 v = x4[tid];
    float ss = v.x * v.x + v.y * v.y + v.z * v.z + v.w * v.w;
    #pragma unroll
    for (int off = 32; off > 0; off >>= 1) ss += __shfl_xor(ss, off, 64);
    __shared__ float sred[4];
    if ((tid & 63) == 0) sred[tid >> 6] = ss;
    __syncthreads();
    float tot = sred[0] + sred[1] + sred[2] + sred[3];
    float scale = rsqrtf(tot * (1.0f / (float)DM) + 1e-6f);
    const float4* w4 = (const float4*)w;
    float4 wv = w4[tid];
    bf16x4 o = { (__bf16)(v.x * scale * wv.x), (__bf16)(v.y * scale * wv.y),
                 (__bf16)(v.z * scale * wv.z), (__bf16)(v.w * scale * wv.w) };
    ((bf16x4*)(xn + (long)row * DM))[tid] = o;
}

// ---------------------------------------------------------------------------
// bf16 MFMA GEMM: 128x128 tile, BK=64 (half the barriers of BK=32), register
// staging, XOR-chunk LDS swizzle (phys_chunk = logical ^ (row&7); row stride
// 64 elems). Both store and read lane sets tile all 32 banks uniformly ->
// conflict-free. Accumulation order identical to R10 (two K-halves in order).
// Epilogue: bf16 store + fp32 dt side-buffer, or fp32 (+resid).
// ---------------------------------------------------------------------------
__global__ __launch_bounds__(256) void k_gemm_bf(const __bf16* __restrict__ A,
                                                 const __bf16* __restrict__ W,
                                                 const float* __restrict__ resid,
                                                 float* __restrict__ Cf,
                                                 __bf16* __restrict__ Cb,
                                                 float* __restrict__ Dt,
                                                 int Nw, int K, int ldc) {
    __shared__ __align__(16) __bf16 As[128 * 64];
    __shared__ __align__(16) __bf16 Bs[128 * 64];
    int t = threadIdx.x;
    int bm = blockIdx.y * 128, bn = blockIdx.x * 128;

    int r0 = t >> 2;             // 0..63
    int lc = t & 3;              // this thread stages logical chunks lc, lc+4
    int r1 = r0 + 64;
    const __bf16* Ag0 = A + (long)(bm + r0) * K + lc * 8;
    const __bf16* Ag1 = A + (long)(bm + r1) * K + lc * 8;
    int br0 = bn + r0; if (br0 >= Nw) br0 = Nw - 1;
    int br1 = bn + r1; if (br1 >= Nw) br1 = Nw - 1;
    const __bf16* Wg0 = W + (long)br0 * K + lc * 8;
    const __bf16* Wg1 = W + (long)br1 * K + lc * 8;

    int sw0  = r0 * 64 + (((lc    ) ^ (r0 & 7)) << 3);
    int sw0b = r0 * 64 + (((lc + 4) ^ (r0 & 7)) << 3);
    int sw1  = r1 * 64 + (((lc    ) ^ (r1 & 7)) << 3);
    int sw1b = r1 * 64 + (((lc + 4) ^ (r1 & 7)) << 3);

    int lane = t & 63, w = t >> 6;
    int wm = (w & 1) * 64, wn = (w >> 1) * 64;
    int ln = lane & 15;
    int q  = lane >> 4;

    f32x4 acc[4][4] = {};

    for (int k0 = 0; k0 < K; k0 += 64) {
        bf16x8 a0  = *(const bf16x8*)(Ag0 + k0);
        bf16x8 a0b = *(const bf16x8*)(Ag0 + k0 + 32);
        bf16x8 a1  = *(const bf16x8*)(Ag1 + k0);
        bf16x8 a1b = *(const bf16x8*)(Ag1 + k0 + 32);
        bf16x8 b0  = *(const bf16x8*)(Wg0 + k0);
        bf16x8 b0b = *(const bf16x8*)(Wg0 + k0 + 32);
        bf16x8 b1  = *(const bf16x8*)(Wg1 + k0);
        bf16x8 b1b = *(const bf16x8*)(Wg1 + k0 + 32);
        __syncthreads();
        *(bf16x8*)(As + sw0)  = a0;  *(bf16x8*)(As + sw0b) = a0b;
        *(bf16x8*)(As + sw1)  = a1;  *(bf16x8*)(As + sw1b) = a1b;
        *(bf16x8*)(Bs + sw0)  = b0;  *(bf16x8*)(Bs + sw0b) = b0b;
        *(bf16x8*)(Bs + sw1)  = b1;  *(bf16x8*)(Bs + sw1b) = b1b;
        __syncthreads();

        #pragma unroll
        for (int h = 0; h < 2; h++) {
            int ch = (4 * h + q);
            int koff = ((ch ^ (ln & 7)) << 3);   // (R&7)==(ln&7): wm,i*16 ≡ 0 mod 8
            bf16x8 af[4], bfr[4];
            #pragma unroll
            for (int i = 0; i < 4; i++)
                af[i]  = *(const bf16x8*)(As + (wm + ln + i * 16) * 64 + koff);
            #pragma unroll
            for (int j = 0; j < 4; j++)
                bfr[j] = *(const bf16x8*)(Bs + (wn + ln + j * 16) * 64 + koff);
            #pragma unroll
            for (int i = 0; i < 4; i++)
                #pragma unroll
                for (int j = 0; j < 4; j++)
                    acc[i][j] = __builtin_amdgcn_mfma_f32_16x16x32_bf16(
                                    af[i], bfr[j], acc[i][j], 0, 0, 0);
        }
    }

    int colbase = bn + wn + ln;
    #pragma unroll
    for (int i = 0; i < 4; i++) {
        #pragma unroll
        for (int r = 0; r < 4; r++) {
            int m = bm + wm + i * 16 + (lane >> 4) * 4 + r;
            long off = (long)m * ldc + colbase;
            #pragma unroll
            for (int j = 0; j < 4; j++) {
                float v = acc[i][j][r];
                if (Cb != nullptr) {
                    Cb[off + j * 16] = (__bf16)v;
                    if (Dt != nullptr) {
                        int col = colbase + j * 16;
                        if (col >= 4352 && col < 4384)
                            Dt[(long)m * 32 + (col - 4352)] = v;
                    }
                } else {
                    if (resid != nullptr) v += resid[off + j * 16];
                    Cf[off + j * 16] = v;
                }
            }
        }
    }
}

// ---------------------------------------------------------------------------
// Phase A (MFMA) fused conv+SiLU+dt/cumlog+D-term; conv reads vectorized
// (b128; p8 is thread-constant, weights preloaded to regs). y out bf16.
// ---------------------------------------------------------------------------
__global__ __launch_bounds__(256) void k_chunk(const __bf16* __restrict__ projb,
                                               const float* __restrict__ dtraw,
                                               const float* __restrict__ cw,
                                               const float* __restrict__ cb,
                                               const float* __restrict__ A_log,
                                               const float* __restrict__ dt_bias,
                                               const float* __restrict__ Dv,
                                               float* __restrict__ clog,
                                               __bf16* __restrict__ yssm,
                                               float* __restrict__ Sloc) {
    int blk = blockIdx.x;
    int c  = blk & 31;
    int hh = (blk >> 5) & 31;
    int b  = blk >> 10;
    int tid = threadIdx.x;
    long rowbase = (long)b * L_SEQ + c * QCH;

    __shared__ __align__(16) __bf16 sB[64 * 136];    // B_chunk [s][n]
    __shared__ __align__(16) __bf16 sU[128 * 72];    // ph1: C [t][n] str136; ph2: B^T [n][s] str72
    __shared__ __align__(16) __bf16 sXT[64 * 72];    // dtx^T [p][s]
    __shared__ __align__(16) __bf16 sXCM[67 * 72];   // ph1: raw x [ss][p]; ph2 overlay: M [t][s]
    __shared__ __align__(16) __bf16 sXCo[64 * 72];   // conv-silu output xc [t][p]
    __shared__ float sCW[256];
    __shared__ float sCB[64];
    __shared__ float sclog[64];
    __shared__ float sdt[64];
    __shared__ float sw[64];

    // ---- stage B, C (bf16 direct) ----
    #pragma unroll
    for (int j = 0; j < 4; j++) {
        int off = j * 256 + tid;          // 1024 bf16x8 = 64 rows * 16
        int t  = off >> 4;
        int n8 = (off & 15) * 8;
        const __bf16* pr = projb + (rowbase + t) * (long)PS;
        *(bf16x8*)&sB[t * 136 + n8] = *(const bf16x8*)(pr + 4096 + n8);
        *(bf16x8*)&sU[t * 136 + n8] = *(const bf16x8*)(pr + 4224 + n8);
    }
    // ---- stage raw x rows ss=0..66 (t = ss-3; zero before seq start) ----
    #pragma unroll
    for (int j = 0; j < 3; j++) {
        int off = j * 256 + tid;          // need 536 = 67 rows * 8 chunks
        if (off < 536) {
            int ss = off >> 3;
            int p8 = (off & 7) * 8;
            bf16x8 xv;
            #pragma unroll
            for (int k = 0; k < 8; k++) xv[k] = (__bf16)0.0f;
            if (c > 0 || ss >= 3)
                xv = *(const bf16x8*)(projb + (rowbase + ss - 3) * (long)PS + DI + hh * HD + p8);
            *(bf16x8*)&sXCM[ss * 72 + p8] = xv;
        }
    }
    sCW[tid] = cw[hh * 256 + tid];
    if (tid < 64) sCB[tid] = cb[hh * 64 + tid];

    // ---- wave 0: dt = softplus (fp32 dtraw), clog = inclusive scan ----
    if (tid < 64) {
        float xr = dtraw[(rowbase + tid) * 32 + hh] + dt_bias[hh];
        float dt = (xr > 20.0f) ? xr : log1pf(expf(xr));
        float la = -expf(A_log[hh]);
        float v = la * dt;
        #pragma unroll
        for (int off = 1; off < 64; off <<= 1) {
            float u = __shfl_up(v, off, 64);
            if (tid >= off) v += u;
        }
        sdt[tid] = dt;
        sclog[tid] = v;
        clog[(rowbase + tid) * NH + hh] = v;
    }
    __syncthreads();

    // ---- conv K=4 + SiLU (vectorized): thread owns fixed p8, two s rows ----
    {
        int p8 = (tid & 7) * 8;
        float wreg[8][4], breg[8];
        #pragma unroll
        for (int e = 0; e < 8; e++) {
            breg[e] = sCB[p8 + e];
            #pragma unroll
            for (int j = 0; j < 4; j++) wreg[e][j] = sCW[(p8 + e) * 4 + j];
        }
        #pragma unroll
        for (int i = 0; i < 2; i++) {
            int s = i * 32 + (tid >> 3);
            bf16x8 r0 = *(const bf16x8*)&sXCM[(s + 0) * 72 + p8];
            bf16x8 r1 = *(const bf16x8*)&sXCM[(s + 1) * 72 + p8];
            bf16x8 r2 = *(const bf16x8*)&sXCM[(s + 2) * 72 + p8];
            bf16x8 r3 = *(const bf16x8*)&sXCM[(s + 3) * 72 + p8];
            float dts = sdt[s];
            bf16x8 oc;
            #pragma unroll
            for (int e = 0; e < 8; e++) {
                float acc = breg[e];
                acc = fmaf(wreg[e][0], (float)r0[e], acc);
                acc = fmaf(wreg[e][1], (float)r1[e], acc);
                acc = fmaf(wreg[e][2], (float)r2[e], acc);
                acc = fmaf(wreg[e][3], (float)r3[e], acc);
                float xc = acc / (1.0f + expf(-acc));
                oc[e] = (__bf16)xc;
                sXT[(p8 + e) * 72 + s] = (__bf16)(dts * xc);
            }
            *(bf16x8*)&sXCo[s * 72 + p8] = oc;
        }
    }
    if (tid < 64) sw[tid] = expf(sclog[63] - sclog[tid]);
    __syncthreads();   // conv reads of sXCM done -> sXCM reusable as sM

    int lane = tid & 63, w = tid >> 6;
    int ln = lane & 15;
    int quad = lane >> 4;
    int kc = quad * 8;

    // ---- G = C @ B^T ----
    bf16x8 caf[4];
    #pragma unroll
    for (int k0 = 0; k0 < 4; k0++)
        caf[k0] = *(const bf16x8*)&sU[(16 * w + ln) * 136 + kc + k0 * 32];
    f32x4 g[4] = {};
    #pragma unroll
    for (int j = 0; j < 4; j++)
        #pragma unroll
        for (int k0 = 0; k0 < 4; k0++) {
            bf16x8 bf_ = *(const bf16x8*)&sB[(16 * j + ln) * 136 + kc + k0 * 32];
            g[j] = __builtin_amdgcn_mfma_f32_16x16x32_bf16(caf[k0], bf_, g[j], 0, 0, 0);
        }

    // ---- M[t,s] = (s<=t) ? exp(clog_t - clog_s) * G : 0 -> sXCM overlay ----
    {
        int trow = 16 * w + quad * 4;
        #pragma unroll
        for (int r = 0; r < 4; r++) {
            int t = trow + r;
            float ct = sclog[t];
            #pragma unroll
            for (int j = 0; j < 4; j++) {
                int s = 16 * j + ln;
                float v = (s <= t) ? g[j][r] * expf(ct - sclog[s]) : 0.0f;
                sXCM[t * 72 + s] = (__bf16)v;
            }
        }
    }
    __syncthreads();   // sM complete; sU (C) now dead

    // ---- transpose sB -> sU as B^T [n][s] (stride 72) ----
    #pragma unroll
    for (int j = 0; j < 4; j++) {
        int s  = tid & 63;
        int n8 = (j * 4 + (tid >> 6)) * 8;
        bf16x8 v = *(const bf16x8*)&sB[s * 136 + n8];
        #pragma unroll
        for (int k = 0; k < 8; k++) sU[(n8 + k) * 72 + s] = v[k];
    }

    // ---- Y = M @ DTX + D[h]*xc  (bf16 out) ----
    {
        float Dh = Dv[hh];
        bf16x8 maf[2];
        #pragma unroll
        for (int k0 = 0; k0 < 2; k0++)
            maf[k0] = *(const bf16x8*)&sXCM[(16 * w + ln) * 72 + kc + k0 * 32];
        f32x4 y[4] = {};
        #pragma unroll
        for (int j = 0; j < 4; j++)
            #pragma unroll
            for (int k0 = 0; k0 < 2; k0++) {
                bf16x8 xf = *(const bf16x8*)&sXT[(16 * j + ln) * 72 + kc + k0 * 32];
                y[j] = __builtin_amdgcn_mfma_f32_16x16x32_bf16(maf[k0], xf, y[j], 0, 0, 0);
            }
        #pragma unroll
        for (int j = 0; j < 4; j++)
            #pragma unroll
            for (int r = 0; r < 4; r++) {
                int t = 16 * w + quad * 4 + r;
                int p = 16 * j + ln;
                float v = y[j][r] + Dh * (float)sXCo[t * 72 + p];
                yssm[(rowbase + t) * DI + hh * HD + p] = (__bf16)v;
            }
    }
    __syncthreads();   // sU (B^T) complete

    // ---- S_loc[p,n] = sum_s w_s * dtx[s,p] * B[s,n] ----
    {
        bf16x8 xaf[2];
        #pragma unroll
        for (int k0 = 0; k0 < 2; k0++) {
            bf16x8 raw = *(const bf16x8*)&sXT[(16 * w + ln) * 72 + kc + k0 * 32];
            bf16x8 sc;
            #pragma unroll
            for (int jj = 0; jj < 8; jj++) {
                int s = kc + k0 * 32 + jj;
                sc[jj] = (__bf16)((float)raw[jj] * sw[s]);
            }
            xaf[k0] = sc;
        }
        f32x4 sacc[8] = {};
        #pragma unroll
        for (int j = 0; j < 8; j++)
            #pragma unroll
            for (int k0 = 0; k0 < 2; k0++) {
                bf16x8 btf = *(const bf16x8*)&sU[(16 * j + ln) * 72 + kc + k0 * 32];
                sacc[j] = __builtin_amdgcn_mfma_f32_16x16x32_bf16(xaf[k0], btf, sacc[j], 0, 0, 0);
            }
        long sbase = ((long)(b * NH + hh) * NC + c) * (HD * DS);
        #pragma unroll
        for (int j = 0; j < 8; j++)
            #pragma unroll
            for (int r = 0; r < 4; r++) {
                int p = 16 * w + quad * 4 + r;
                int n = 16 * j + ln;
                Sloc[sbase + p * DS + n] = sacc[j][r];
            }
    }
}

// ---------------------------------------------------------------------------
// Fused: carry [blocks 0..2047] + f2b(Wo) [blocks 2048..4095].
// Independent data: carry touches Sloc/clog; f2b reads Wo, writes Wob
// (Wob has its OWN slot — Sloc is still live for k_fix).
// ---------------------------------------------------------------------------
__global__ __launch_bounds__(256) void k_carry_f2b(float* __restrict__ Sloc,
                                                   const float* __restrict__ clog,
                                                   const float* __restrict__ Wo,
                                                   __bf16* __restrict__ Wob) {
    int bid = blockIdx.x;
    int tid = threadIdx.x;
    if (bid >= 2048) {
        int i = (bid - 2048) * 256 + tid;    // < (DM*DI)/4
        float4 v = ((const float4*)Wo)[i];
        bf16x4 o = { (__bf16)v.x, (__bf16)v.y, (__bf16)v.z, (__bf16)v.w };
        ((bf16x4*)Wob)[i] = o;
        return;
    }
    int idx = bid * 256 + tid;               // < 524288
    int n  = idx & 127;
    int p  = (idx >> 7) & 63;
    int hh = (idx >> 13) & 31;
    int b  = idx >> 18;
    long base = ((long)(b * NH + hh) * NC) * (HD * DS) + p * DS + n;
    float T = 0.0f;
    for (int c = 0; c < NC; c++) {
        float lam = expf(clog[((long)b * L_SEQ + c * QCH + QCH - 1) * NH + hh]);
        long a = base + (long)c * (HD * DS);
        float S = Sloc[a];
        Sloc[a] = T;
        T = fmaf(T, lam, S);
    }
}

// ---------------------------------------------------------------------------
// Phase C + gate (MFMA): Ycorr = C_chunk @ Hin^T, then
// yg = (yb + exp(clog_t)*Ycorr) * silu(z), bf16 out. yb now bf16.
// ---------------------------------------------------------------------------
__global__ __launch_bounds__(256, 2) void k_fix(const __bf16* __restrict__ projb,
                                                const float* __restrict__ Sloc,
                                                const float* __restrict__ clog,
                                                const __bf16* __restrict__ yb,
                                                __bf16* __restrict__ yg) {
    int blk = blockIdx.x;
    int c  = blk & 31;
    int hh = (blk >> 5) & 31;
    int b  = blk >> 10;

    __shared__ __align__(16) __bf16 sC[64 * 136];   // C [t][n]
    __shared__ __align__(16) __bf16 sH[64 * 136];   // Hin [p][n]
    __shared__ float sP[64];

    int tid = threadIdx.x;
    long hbase = ((long)(b * NH + hh) * NC + c) * (HD * DS);
    long rowbase = (long)b * L_SEQ + c * QCH;

    #pragma unroll
    for (int j = 0; j < 4; j++) {
        int off = j * 256 + tid;          // 1024 bf16x8
        int t  = off >> 4;
        int n8 = (off & 15) * 8;
        *(bf16x8*)&sC[t * 136 + n8] =
            *(const bf16x8*)(projb + (rowbase + t) * (long)PS + 4224 + n8);
    }
    #pragma unroll
    for (int j = 0; j < 8; j++) {
        int off = j * 256 + tid;          // 2048 float4
        int p  = off >> 5;
        int n4 = (off & 31) * 4;
        float4 hv = *(const float4*)&Sloc[hbase + (long)off * 4];
        bf16x4 hb = {(__bf16)hv.x, (__bf16)hv.y, (__bf16)hv.z, (__bf16)hv.w};
        *(bf16x4*)&sH[p * 136 + n4] = hb;
    }
    if (tid < 64) sP[tid] = expf(clog[(rowbase + tid) * NH + hh]);
    __syncthreads();

    int lane = tid & 63, w = tid >> 6;
    int ln = lane & 15;
    int quad = lane >> 4;
    int kc = quad * 8;

    bf16x8 caf[4];
    #pragma unroll
    for (int k0 = 0; k0 < 4; k0++)
        caf[k0] = *(const bf16x8*)&sC[(16 * w + ln) * 136 + kc + k0 * 32];
    f32x4 acc4[4] = {};
    #pragma unroll
    for (int j = 0; j < 4; j++)
        #pragma unroll
        for (int k0 = 0; k0 < 4; k0++) {
            bf16x8 hf = *(const bf16x8*)&sH[(16 * j + ln) * 136 + kc + k0 * 32];
            acc4[j] = __builtin_amdgcn_mfma_f32_16x16x32_bf16(caf[k0], hf, acc4[j], 0, 0, 0);
        }

    #pragma unroll
    for (int j = 0; j < 4; j++)
        #pragma unroll
        for (int r = 0; r < 4; r++) {
            int t = 16 * w + quad * 4 + r;
            int p = 16 * j + ln;
            long row = rowbase + t;
            long yoff = row * DI + hh * HD + p;
            float pm = sP[t];
            float z = (float)projb[row * (long)PS + hh * HD + p];
            float o = ((float)yb[yoff] + pm * acc4[j][r]) * (z / (1.0f + expf(-z)));
            yg[yoff] = (__bf16)o;
        }
}

// ---------------------------------------------------------------------------
extern "C" void kernel_launch(void* const* d_in, const int* in_sizes, int n_in,
                              void* d_out, int out_size, void* d_ws, size_t ws_size,
                              hipStream_t stream) {
    const float* x       = (const float*)d_in[0];
    const float* norm_w  = (const float*)d_in[1];
    const float* Wp      = (const float*)d_in[2];   // (4384, 1024)
    const float* cw      = (const float*)d_in[3];
    const float* cb      = (const float*)d_in[4];
    const float* A_log   = (const float*)d_in[5];
    const float* Dv      = (const float*)d_in[6];
    const float* dt_bias = (const float*)d_in[7];
    const float* Wo      = (const float*)d_in[8];   // (1024, 2048)
    float* out = (float*)d_out;

    // workspace (float units):
    float* ws     = (float*)d_ws;
    __bf16* projb = (__bf16*)ws;              //  9,175,040 fl (18,350,080 bf16)
    float* dtraw  = ws    + 9175040;          //    131,072
    float* clog   = dtraw + 131072;           //    131,072
    float* ybh    = clog  + 131072;           //  4,194,304 fl (yb bf16)
    float* ybf    = ybh   + 4194304;          //  4,194,304 fl (ybb bf16)
    float* wob_s  = ybf   + 4194304;          //  1,048,576 fl (Wob bf16) — own
                                              //  slot: Sloc live during f2b(Wo)
    float* U      = wob_s + 1048576;          // 16,777,216
    // total 35,651,584 floats = 142.6 MB

    __bf16* xnb  = (__bf16*)U;
    __bf16* Wpb  = (__bf16*)(U + 2097152);
    float*  Sloc = U;                         // exactly 16,777,216 fl
    __bf16* Wob  = (__bf16*)wob_s;
    __bf16* ybb  = (__bf16*)ybf;
    __bf16* yb   = (__bf16*)ybh;

    // phase 1: f2b(Wp) + rmsnorm fused, then in_proj GEMM
    k_prep<<<4384 + M_ROWS, 256, 0, stream>>>(Wp, Wpb, x, norm_w, xnb);
    {
        dim3 g(PS / 128, M_ROWS / 128);
        k_gemm_bf<<<g, 256, 0, stream>>>(xnb, Wpb, nullptr, nullptr, projb,
                                         dtraw, DP, DM, PS);
    }

    // phase 2: chunked scan (Sloc overwrites xnb/Wpb — dead)
    k_chunk<<<B_SZ * NH * NC, 256, 0, stream>>>(projb, dtraw, cw, cb, A_log,
                                                dt_bias, Dv, clog, yb, Sloc);
    k_carry_f2b<<<4096, 256, 0, stream>>>(Sloc, clog, Wo, Wob);
    k_fix<<<B_SZ * NH * NC, 256, 0, stream>>>(projb, Sloc, clog, yb, ybb);

    // phase 3: out_proj
    {
        dim3 g(DM / 128, M_ROWS / 128);
        k_gemm_bf<<<g, 256, 0, stream>>>(ybb, Wob, x, out, nullptr, nullptr,
                                         DM, DI, DM);
    }
}